// Round 1
// baseline (2000.267 us; speedup 1.0000x reference)
//
#include <hip/hip_runtime.h>

#define BATCH 2
#define SEQ 512
#define DMODEL 512
#define DINNER 1024
#define DSTATE 16
#define DTRANK 32
#define NBL (BATCH*SEQ)      // 1024
#define EPSV 1e-5f

static __device__ __forceinline__ float sigmoidf_(float x) {
  return 1.0f / (1.0f + __expf(-x));
}
static __device__ __forceinline__ float softplusf_(float x) {
  return fmaxf(x, 0.0f) + log1pf(__expf(-fabsf(x)));
}

// ---------------- fused add + RMSNorm ----------------
// row = b*SEQ + l; D = 512; block 256, each thread 2 elems.
__global__ __launch_bounds__(256) void addnorm_kernel(
    const float* __restrict__ hs, float* __restrict__ residual,
    const float* __restrict__ w, float* __restrict__ out, int first) {
  const int row = blockIdx.x;
  const int t = threadIdx.x;
  const float* hp = hs + (long)row * DMODEL;
  float* rp = residual + (long)row * DMODEL;
  float r0 = hp[t], r1 = hp[t + 256];
  if (!first) { r0 += rp[t]; r1 += rp[t + 256]; }
  rp[t] = r0; rp[t + 256] = r1;
  float ss = r0 * r0 + r1 * r1;
  #pragma unroll
  for (int off = 32; off; off >>= 1) ss += __shfl_xor(ss, off, 64);
  __shared__ float sw[4];
  const int wid = t >> 6, lane = t & 63;
  if (lane == 0) sw[wid] = ss;
  __syncthreads();
  const float tot = sw[0] + sw[1] + sw[2] + sw[3];
  const float scale = rsqrtf(tot * (1.0f / (float)DMODEL) + EPSV);
  out[(long)row * DMODEL + t] = r0 * scale * w[t];
  out[(long)row * DMODEL + t + 256] = r1 * scale * w[t + 256];
}

// ---------------- tiled fp32 GEMM 64x64x16 ----------------
// C[m,n] = sum_k A[m,k] * B[k,n]   (bt=0: B is (K,N) row-major, optional +B2)
//                                  (bt=1: B is (N,K) row-major)
// store C[m*ldm + n*ldn]; optional duplicate store to C2.
__global__ __launch_bounds__(256) void gemm64_kernel(
    const float* __restrict__ A, const float* __restrict__ Bm,
    const float* __restrict__ B2, float* __restrict__ C, float* __restrict__ C2,
    int M, int N, int K, int ldm, int ldn, int bt) {
  __shared__ float As[16][68];
  __shared__ float Bs[16][68];
  const int t = threadIdx.x;
  const int m0 = blockIdx.y * 64, n0 = blockIdx.x * 64;
  const int tx = t & 15, ty = t >> 4;
  float acc[4][4] = {};
  for (int k0 = 0; k0 < K; k0 += 16) {
    {
      const int kk = t & 15, mm = t >> 4;
      #pragma unroll
      for (int r = 0; r < 4; ++r)
        As[kk][mm + r * 16] = A[(long)(m0 + mm + r * 16) * K + (k0 + kk)];
    }
    if (bt) {
      const int kk = t & 15, nn = t >> 4;
      #pragma unroll
      for (int r = 0; r < 4; ++r)
        Bs[kk][nn + r * 16] = Bm[(long)(n0 + nn + r * 16) * K + (k0 + kk)];
    } else {
      const int nn = t & 63, kk4 = t >> 6;
      #pragma unroll
      for (int r = 0; r < 4; ++r) {
        const int k = kk4 + r * 4;
        float v = Bm[(long)(k0 + k) * N + (n0 + nn)];
        if (B2) v += B2[(long)(k0 + k) * N + (n0 + nn)];
        Bs[k][nn] = v;
      }
    }
    __syncthreads();
    #pragma unroll
    for (int k = 0; k < 16; ++k) {
      const float4 a4 = *(const float4*)&As[k][ty * 4];
      const float4 b4 = *(const float4*)&Bs[k][tx * 4];
      const float av[4] = {a4.x, a4.y, a4.z, a4.w};
      const float bv[4] = {b4.x, b4.y, b4.z, b4.w};
      #pragma unroll
      for (int i = 0; i < 4; ++i)
        #pragma unroll
        for (int j = 0; j < 4; ++j)
          acc[i][j] = fmaf(av[i], bv[j], acc[i][j]);
    }
    __syncthreads();
  }
  #pragma unroll
  for (int i = 0; i < 4; ++i)
    #pragma unroll
    for (int j = 0; j < 4; ++j) {
      const long addr = (long)(m0 + ty * 4 + i) * ldm + (long)(n0 + tx * 4 + j) * ldn;
      C[addr] = acc[i][j];
      if (C2) C2[addr] = acc[i][j];
    }
}

// ---------------- depthwise causal conv (K=4) + SiLU, both dirs ----------------
// xz layout (e=2048, b, l); xi = rows [0,1024). Output xconv (d, b, l), per dir.
__global__ __launch_bounds__(256) void conv_silu_kernel(
    const float* __restrict__ xz,
    const float* __restrict__ cw_f, const float* __restrict__ cb_f,
    const float* __restrict__ cw_r, const float* __restrict__ cb_r,
    float* __restrict__ xconv_f, float* __restrict__ xconv_r) {
  const int dir = blockIdx.y;
  const int idx = blockIdx.x * 256 + threadIdx.x;  // over DINNER*BATCH*SEQ
  const int l = idx & (SEQ - 1);
  const int bd = idx >> 9;
  const int b = bd & 1, d = bd >> 1;
  const float* cw = dir ? cw_r : cw_f;
  const float* cb = dir ? cb_r : cb_f;
  const float* xi = xz + (long)d * NBL + b * SEQ;
  float sum = cb[d];
  #pragma unroll
  for (int k = 0; k < 4; ++k) {
    const int tt = l - 3 + k;
    if (tt >= 0) {
      const int src = dir ? (SEQ - 1 - tt) : tt;
      sum += cw[d * 4 + k] * xi[src];
    }
  }
  const float v = sum * sigmoidf_(sum);
  (dir ? xconv_r : xconv_f)[idx] = v;
}

// ---------------- x_dbl = xpw @ xconv ----------------
// writes dt rows (0..31) to xdbl (r, n) and B/C rows transposed to xbc (n, 32):
// xbc[n*32 + j]    = B_j (row 32+j)
// xbc[n*32 + 16+j] = C_j (row 48+j)
__global__ __launch_bounds__(256) void xdbl_kernel(
    const float* __restrict__ xconv_f, const float* __restrict__ xconv_r,
    const float* __restrict__ xpw_f, const float* __restrict__ xpw_r,
    float* __restrict__ xdbl_f, float* __restrict__ xdbl_r,
    float* __restrict__ xbc_f, float* __restrict__ xbc_r) {
  const int dir = blockIdx.y;
  const int idx = blockIdx.x * 256 + threadIdx.x;  // 16 rgroups * 1024 n
  const int n = idx & (NBL - 1);
  const int rg = idx >> 10;  // 0..15
  const float* xc = dir ? xconv_r : xconv_f;
  const float* xpw = dir ? xpw_r : xpw_f;
  float a0 = 0.f, a1 = 0.f, a2 = 0.f, a3 = 0.f;
  #pragma unroll 8
  for (int e = 0; e < DINNER; ++e) {
    const float xv = xc[(long)e * NBL + n];
    a0 = fmaf(xpw[(rg) * DINNER + e], xv, a0);
    a1 = fmaf(xpw[(rg + 16) * DINNER + e], xv, a1);
    a2 = fmaf(xpw[(rg + 32) * DINNER + e], xv, a2);
    a3 = fmaf(xpw[(rg + 48) * DINNER + e], xv, a3);
  }
  float* xd = dir ? xdbl_r : xdbl_f;
  float* xbc = dir ? xbc_r : xbc_f;
  xd[(long)(rg) * NBL + n] = a0;
  xd[(long)(rg + 16) * NBL + n] = a1;
  xbc[(long)n * 32 + rg] = a2;
  xbc[(long)n * 32 + 16 + rg] = a3;
}

// ---------------- delta = softplus(dtw @ dt + dtb) ----------------
__global__ __launch_bounds__(256) void delta_kernel(
    const float* __restrict__ xdbl_f, const float* __restrict__ xdbl_r,
    const float* __restrict__ dtw_f, const float* __restrict__ dtw_r,
    const float* __restrict__ dtb_f, const float* __restrict__ dtb_r,
    float* __restrict__ delta_f, float* __restrict__ delta_r) {
  const int dir = blockIdx.y;
  const int idx = blockIdx.x * 256 + threadIdx.x;  // 256 dgroups * 1024 n
  const int n = idx & (NBL - 1);
  const int dg = idx >> 10;  // 0..255
  const float* xd = dir ? xdbl_r : xdbl_f;
  const float* dtw = dir ? dtw_r : dtw_f;
  const float* dtb = dir ? dtb_r : dtb_f;
  float acc[4];
  #pragma unroll
  for (int j = 0; j < 4; ++j) acc[j] = dtb[dg + 256 * j];
  #pragma unroll
  for (int r = 0; r < DTRANK; ++r) {
    const float xv = xd[(long)r * NBL + n];
    #pragma unroll
    for (int j = 0; j < 4; ++j)
      acc[j] = fmaf(dtw[(dg + 256 * j) * DTRANK + r], xv, acc[j]);
  }
  float* dl = dir ? delta_r : delta_f;
  #pragma unroll
  for (int j = 0; j < 4; ++j)
    dl[(long)(dg + 256 * j) * NBL + n] = softplusf_(acc[j]);
}

// ---------------- selective scan + Dskip + SiLU(z) gate ----------------
// 16 lanes per (dir, b, d) group; lane = state index n.
__global__ __launch_bounds__(256) void scan_kernel(
    const float* __restrict__ xz,
    const float* __restrict__ xconv_f, const float* __restrict__ xconv_r,
    const float* __restrict__ delta_f, const float* __restrict__ delta_r,
    const float* __restrict__ xbc_f, const float* __restrict__ xbc_r,
    const float* __restrict__ Alog_f, const float* __restrict__ Alog_r,
    const float* __restrict__ Dsk_f, const float* __restrict__ Dsk_r,
    float* __restrict__ y_f, float* __restrict__ y_r) {
  const int gid = (blockIdx.x << 4) + (threadIdx.x >> 4);
  const int lane = threadIdx.x & 15;
  const int dir = gid >> 11;
  const int g2 = gid & 2047;
  const int b = g2 & 1;
  const int d = g2 >> 1;
  const float* Alog = dir ? Alog_r : Alog_f;
  const float* Dsk = dir ? Dsk_r : Dsk_f;
  const float* dp = (dir ? delta_r : delta_f) + (long)d * NBL + b * SEQ;
  const float* up = (dir ? xconv_r : xconv_f) + (long)d * NBL + b * SEQ;
  const float* bc = (dir ? xbc_r : xbc_f) + (long)b * SEQ * 32;
  const float* zp = xz + (long)(DINNER + d) * NBL + b * SEQ;
  float* yp = (dir ? y_r : y_f) + (long)d * NBL + b * SEQ;
  const float An = -__expf(Alog[d * DSTATE + lane]);
  const float Dv = Dsk[d];
  float h = 0.0f;
  for (int l = 0; l < SEQ; ++l) {
    const float dt = dp[l];
    const float u = up[l];
    const float Bn = bc[l * 32 + lane];
    const float Cn = bc[l * 32 + 16 + lane];
    const float dA = __expf(dt * An);
    h = fmaf(h, dA, dt * u * Bn);
    float p = h * Cn;
    p += __shfl_xor(p, 1, 16);
    p += __shfl_xor(p, 2, 16);
    p += __shfl_xor(p, 4, 16);
    p += __shfl_xor(p, 8, 16);
    if (lane == 0) {
      const int lo = dir ? (SEQ - 1 - l) : l;
      const float z = zp[lo];
      yp[lo] = (p + Dv * u) * (z * sigmoidf_(z));
    }
  }
}

extern "C" void kernel_launch(void* const* d_in, const int* in_sizes, int n_in,
                              void* d_out, int out_size, void* d_ws, size_t ws_size,
                              hipStream_t stream) {
  (void)in_sizes; (void)n_in; (void)out_size; (void)ws_size;
  const float* x       = (const float*)d_in[0];
  const float* norm_w  = (const float*)d_in[1];
  const float* in_proj = (const float*)d_in[2];
  const float* convw_f = (const float*)d_in[3];
  const float* convb_f = (const float*)d_in[4];
  const float* xpw_f   = (const float*)d_in[5];
  const float* dtw_f   = (const float*)d_in[6];
  const float* dtb_f   = (const float*)d_in[7];
  const float* Alog_f  = (const float*)d_in[8];
  const float* Dsk_f   = (const float*)d_in[9];
  const float* convw_r = (const float*)d_in[10];
  const float* convb_r = (const float*)d_in[11];
  const float* xpw_r   = (const float*)d_in[12];
  const float* dtw_r   = (const float*)d_in[13];
  const float* dtb_r   = (const float*)d_in[14];
  const float* Alog_r  = (const float*)d_in[15];
  const float* Dsk_r   = (const float*)d_in[16];
  const float* out_w   = (const float*)d_in[17];
  const float* normf_w = (const float*)d_in[18];

  float* ws = (float*)d_ws;
  float* residual = ws;  ws += 524288;
  float* hn       = ws;  ws += 524288;
  float* xzbuf    = ws;  ws += 2097152;
  float* xconv_f  = ws;  ws += 1048576;
  float* xconv_r  = ws;  ws += 1048576;
  float* xdbl_f   = ws;  ws += 32768;
  float* xdbl_r   = ws;  ws += 32768;
  float* xbc_f    = ws;  ws += 32768;
  float* xbc_r    = ws;  ws += 32768;
  float* delta_f  = ws;  ws += 1048576;
  float* delta_r  = ws;  ws += 1048576;
  float* y_f      = ws;  ws += 1048576;
  float* y_r      = ws;  ws += 1048576;
  float* hs       = ws;  ws += 524288;

  float* outp = (float*)d_out;

  for (int layer = 0; layer < 4; ++layer) {
    addnorm_kernel<<<1024, 256, 0, stream>>>(
        layer == 0 ? x : hs, residual, norm_w + layer * DMODEL, hn, layer == 0 ? 1 : 0);
    gemm64_kernel<<<dim3(16, 32), 256, 0, stream>>>(
        in_proj + (long)layer * 2048 * 512, hn, nullptr, xzbuf, nullptr,
        2048, 1024, 512, 1024, 1, 1);
    conv_silu_kernel<<<dim3(4096, 2), 256, 0, stream>>>(
        xzbuf, convw_f + layer * DINNER * 4, convb_f + layer * DINNER,
        convw_r + layer * DINNER * 4, convb_r + layer * DINNER, xconv_f, xconv_r);
    xdbl_kernel<<<dim3(64, 2), 256, 0, stream>>>(
        xconv_f, xconv_r, xpw_f + layer * 64 * DINNER, xpw_r + layer * 64 * DINNER,
        xdbl_f, xdbl_r, xbc_f, xbc_r);
    delta_kernel<<<dim3(1024, 2), 256, 0, stream>>>(
        xdbl_f, xdbl_r, dtw_f + layer * DINNER * DTRANK, dtw_r + layer * DINNER * DTRANK,
        dtb_f + layer * DINNER, dtb_r + layer * DINNER, delta_f, delta_r);
    scan_kernel<<<256, 256, 0, stream>>>(
        xzbuf, xconv_f, xconv_r, delta_f, delta_r, xbc_f, xbc_r,
        Alog_f + layer * DINNER * DSTATE, Alog_r + layer * DINNER * DSTATE,
        Dsk_f + layer * DINNER, Dsk_r + layer * DINNER, y_f, y_r);
    gemm64_kernel<<<dim3(16, 8), 256, 0, stream>>>(
        out_w + (long)layer * 512 * 1024, y_f, y_r, hs,
        outp + (long)(1 + layer) * 524288,
        512, 1024, 1024, 1, 512, 0);
  }
  addnorm_kernel<<<1024, 256, 0, stream>>>(hs, residual, normf_w, outp, 0);
}

// Round 2
// 1419.164 us; speedup vs baseline: 1.4095x; 1.4095x over previous
//
#include <hip/hip_runtime.h>

#define BATCH 2
#define SEQ 512
#define DMODEL 512
#define DINNER 1024
#define DSTATE 16
#define DTRANK 32
#define NBL (BATCH*SEQ)      // 1024
#define EPSV 1e-5f

static __device__ __forceinline__ float sigmoidf_(float x) {
  return 1.0f / (1.0f + __expf(-x));
}
static __device__ __forceinline__ float softplusf_(float x) {
  return fmaxf(x, 0.0f) + log1pf(__expf(-fabsf(x)));
}

// ---------------- fused add + RMSNorm ----------------
__global__ __launch_bounds__(256) void addnorm_kernel(
    const float* __restrict__ hs, float* __restrict__ residual,
    const float* __restrict__ w, float* __restrict__ out, int first) {
  const int row = blockIdx.x;
  const int t = threadIdx.x;
  const float* hp = hs + (long)row * DMODEL;
  float* rp = residual + (long)row * DMODEL;
  float r0 = hp[t], r1 = hp[t + 256];
  if (!first) { r0 += rp[t]; r1 += rp[t + 256]; }
  rp[t] = r0; rp[t + 256] = r1;
  float ss = r0 * r0 + r1 * r1;
  #pragma unroll
  for (int off = 32; off; off >>= 1) ss += __shfl_xor(ss, off, 64);
  __shared__ float sw[4];
  const int wid = t >> 6, lane = t & 63;
  if (lane == 0) sw[wid] = ss;
  __syncthreads();
  const float tot = sw[0] + sw[1] + sw[2] + sw[3];
  const float scale = rsqrtf(tot * (1.0f / (float)DMODEL) + EPSV);
  out[(long)row * DMODEL + t] = r0 * scale * w[t];
  out[(long)row * DMODEL + t + 256] = r1 * scale * w[t + 256];
}

// ---------------- tiled fp32 GEMM 64x64x16 ----------------
__global__ __launch_bounds__(256) void gemm64_kernel(
    const float* __restrict__ A, const float* __restrict__ Bm,
    const float* __restrict__ B2, float* __restrict__ C, float* __restrict__ C2,
    int M, int N, int K, int ldm, int ldn, int bt) {
  __shared__ float As[16][68];
  __shared__ float Bs[16][68];
  const int t = threadIdx.x;
  const int m0 = blockIdx.y * 64, n0 = blockIdx.x * 64;
  const int tx = t & 15, ty = t >> 4;
  float acc[4][4] = {};
  for (int k0 = 0; k0 < K; k0 += 16) {
    {
      const int kk = t & 15, mm = t >> 4;
      #pragma unroll
      for (int r = 0; r < 4; ++r)
        As[kk][mm + r * 16] = A[(long)(m0 + mm + r * 16) * K + (k0 + kk)];
    }
    if (bt) {
      const int kk = t & 15, nn = t >> 4;
      #pragma unroll
      for (int r = 0; r < 4; ++r)
        Bs[kk][nn + r * 16] = Bm[(long)(n0 + nn + r * 16) * K + (k0 + kk)];
    } else {
      const int nn = t & 63, kk4 = t >> 6;
      #pragma unroll
      for (int r = 0; r < 4; ++r) {
        const int k = kk4 + r * 4;
        float v = Bm[(long)(k0 + k) * N + (n0 + nn)];
        if (B2) v += B2[(long)(k0 + k) * N + (n0 + nn)];
        Bs[k][nn] = v;
      }
    }
    __syncthreads();
    #pragma unroll
    for (int k = 0; k < 16; ++k) {
      const float4 a4 = *(const float4*)&As[k][ty * 4];
      const float4 b4 = *(const float4*)&Bs[k][tx * 4];
      const float av[4] = {a4.x, a4.y, a4.z, a4.w};
      const float bv[4] = {b4.x, b4.y, b4.z, b4.w};
      #pragma unroll
      for (int i = 0; i < 4; ++i)
        #pragma unroll
        for (int j = 0; j < 4; ++j)
          acc[i][j] = fmaf(av[i], bv[j], acc[i][j]);
    }
    __syncthreads();
  }
  #pragma unroll
  for (int i = 0; i < 4; ++i)
    #pragma unroll
    for (int j = 0; j < 4; ++j) {
      const long addr = (long)(m0 + ty * 4 + i) * ldm + (long)(n0 + tx * 4 + j) * ldn;
      C[addr] = acc[i][j];
      if (C2) C2[addr] = acc[i][j];
    }
}

// ---------------- depthwise causal conv (K=4) + SiLU, both dirs ----------------
__global__ __launch_bounds__(256) void conv_silu_kernel(
    const float* __restrict__ xz,
    const float* __restrict__ cw_f, const float* __restrict__ cb_f,
    const float* __restrict__ cw_r, const float* __restrict__ cb_r,
    float* __restrict__ xconv_f, float* __restrict__ xconv_r) {
  const int dir = blockIdx.y;
  const int idx = blockIdx.x * 256 + threadIdx.x;
  const int l = idx & (SEQ - 1);
  const int bd = idx >> 9;
  const int b = bd & 1, d = bd >> 1;
  const float* cw = dir ? cw_r : cw_f;
  const float* cb = dir ? cb_r : cb_f;
  const float* xi = xz + (long)d * NBL + b * SEQ;
  float sum = cb[d];
  #pragma unroll
  for (int k = 0; k < 4; ++k) {
    const int tt = l - 3 + k;
    if (tt >= 0) {
      const int src = dir ? (SEQ - 1 - tt) : tt;
      sum += cw[d * 4 + k] * xi[src];
    }
  }
  const float v = sum * sigmoidf_(sum);
  (dir ? xconv_r : xconv_f)[idx] = v;
}

// ---------------- x_dbl = xpw @ xconv ----------------
__global__ __launch_bounds__(256) void xdbl_kernel(
    const float* __restrict__ xconv_f, const float* __restrict__ xconv_r,
    const float* __restrict__ xpw_f, const float* __restrict__ xpw_r,
    float* __restrict__ xdbl_f, float* __restrict__ xdbl_r,
    float* __restrict__ xbc_f, float* __restrict__ xbc_r) {
  const int dir = blockIdx.y;
  const int idx = blockIdx.x * 256 + threadIdx.x;
  const int n = idx & (NBL - 1);
  const int rg = idx >> 10;  // 0..15
  const float* xc = dir ? xconv_r : xconv_f;
  const float* xpw = dir ? xpw_r : xpw_f;
  float a0 = 0.f, a1 = 0.f, a2 = 0.f, a3 = 0.f;
  #pragma unroll 8
  for (int e = 0; e < DINNER; ++e) {
    const float xv = xc[(long)e * NBL + n];
    a0 = fmaf(xpw[(rg) * DINNER + e], xv, a0);
    a1 = fmaf(xpw[(rg + 16) * DINNER + e], xv, a1);
    a2 = fmaf(xpw[(rg + 32) * DINNER + e], xv, a2);
    a3 = fmaf(xpw[(rg + 48) * DINNER + e], xv, a3);
  }
  float* xd = dir ? xdbl_r : xdbl_f;
  float* xbc = dir ? xbc_r : xbc_f;
  xd[(long)(rg) * NBL + n] = a0;
  xd[(long)(rg + 16) * NBL + n] = a1;
  xbc[(long)n * 32 + rg] = a2;
  xbc[(long)n * 32 + 16 + rg] = a3;
}

// ---------------- delta = softplus(dtw @ dt + dtb) ----------------
__global__ __launch_bounds__(256) void delta_kernel(
    const float* __restrict__ xdbl_f, const float* __restrict__ xdbl_r,
    const float* __restrict__ dtw_f, const float* __restrict__ dtw_r,
    const float* __restrict__ dtb_f, const float* __restrict__ dtb_r,
    float* __restrict__ delta_f, float* __restrict__ delta_r) {
  const int dir = blockIdx.y;
  const int idx = blockIdx.x * 256 + threadIdx.x;
  const int n = idx & (NBL - 1);
  const int dg = idx >> 10;  // 0..255
  const float* xd = dir ? xdbl_r : xdbl_f;
  const float* dtw = dir ? dtw_r : dtw_f;
  const float* dtb = dir ? dtb_r : dtb_f;
  float acc[4];
  #pragma unroll
  for (int j = 0; j < 4; ++j) acc[j] = dtb[dg + 256 * j];
  #pragma unroll
  for (int r = 0; r < DTRANK; ++r) {
    const float xv = xd[(long)r * NBL + n];
    #pragma unroll
    for (int j = 0; j < 4; ++j)
      acc[j] = fmaf(dtw[(dg + 256 * j) * DTRANK + r], xv, acc[j]);
  }
  float* dl = dir ? delta_r : delta_f;
  #pragma unroll
  for (int j = 0; j < 4; ++j)
    dl[(long)(dg + 256 * j) * NBL + n] = softplusf_(acc[j]);
}

// ---------------- selective scan, LDS-staged + prefetch ----------------
// block = 256 threads = 16 groups of 16 lanes; block handles (dir, b, 16 d's).
// chunk = 32 steps, double-buffered LDS; next chunk prefetched to regs a full
// chunk early (T14) so HBM/L2 latency hides under the 32 unrolled scan steps.
#define CHT 32
#define NCH (SEQ / CHT)
__global__ __launch_bounds__(256) void scan_kernel(
    const float* __restrict__ xz,
    const float* __restrict__ xconv_f, const float* __restrict__ xconv_r,
    const float* __restrict__ delta_f, const float* __restrict__ delta_r,
    const float* __restrict__ xbc_f, const float* __restrict__ xbc_r,
    const float* __restrict__ Alog_f, const float* __restrict__ Alog_r,
    const float* __restrict__ Dsk_f, const float* __restrict__ Dsk_r,
    float* __restrict__ y_f, float* __restrict__ y_r) {
  __shared__ float s_dt[2][16][CHT + 1];
  __shared__ float s_u[2][16][CHT + 1];
  __shared__ float s_z[2][16][CHT + 1];
  __shared__ float s_y[2][16][CHT + 1];
  __shared__ float s_bc[2][CHT * 32];

  const int t = threadIdx.x;
  const int bx = blockIdx.x;           // 256 blocks
  const int dir = bx >> 7;
  const int b = (bx >> 6) & 1;
  const int d0 = (bx & 63) << 4;
  const int g = t >> 4;                // group within block -> d = d0+g
  const int lane = t & 15;             // state index

  const float* dpB = (dir ? delta_r : delta_f);
  const float* upB = (dir ? xconv_r : xconv_f);
  const float* bcB = (dir ? xbc_r : xbc_f) + (long)b * SEQ * 32;
  const float* Alog = dir ? Alog_r : Alog_f;
  const float* Dsk = dir ? Dsk_r : Dsk_f;
  float* ypB = (dir ? y_r : y_f);

  const int d = d0 + g;
  const float An = -__expf(Alog[d * DSTATE + lane]);
  const float Dv = Dsk[d];

  // per-thread staging indices (2 elems of 512 per array)
  const int e0g = t >> 5, e0s = t & 31;          // elem t
  const int e1g = (t + 256) >> 5, e1s = t & 31;  // elem t+256 (same low5 bits)
  const long row0 = (long)(d0 + e0g) * NBL + b * SEQ;
  const long row1 = (long)(d0 + e1g) * NBL + b * SEQ;
  const long zrow0 = (long)(DINNER + d0 + e0g) * NBL + b * SEQ;
  const long zrow1 = (long)(DINNER + d0 + e1g) * NBL + b * SEQ;

  float r_dt0, r_dt1, r_u0, r_u1, r_z0, r_z1;
  float4 r_bc;

  #define LOADC(c) do {                                                   \
    const int l0_ = (c) << 5;                                             \
    r_dt0 = dpB[row0 + l0_ + e0s]; r_dt1 = dpB[row1 + l0_ + e1s];         \
    r_u0 = upB[row0 + l0_ + e0s];  r_u1 = upB[row1 + l0_ + e1s];          \
    const int lo0_ = dir ? (SEQ - 1 - (l0_ + e0s)) : (l0_ + e0s);         \
    const int lo1_ = dir ? (SEQ - 1 - (l0_ + e1s)) : (l0_ + e1s);         \
    r_z0 = xz[zrow0 + lo0_]; r_z1 = xz[zrow1 + lo1_];                     \
    r_bc = *(const float4*)&bcB[(l0_ << 5) + (t << 2)];                   \
  } while (0)

  #define STOREC(buf) do {                                                \
    s_dt[buf][e0g][e0s] = r_dt0; s_dt[buf][e1g][e1s] = r_dt1;             \
    s_u[buf][e0g][e0s] = r_u0;   s_u[buf][e1g][e1s] = r_u1;               \
    s_z[buf][e0g][e0s] = r_z0;   s_z[buf][e1g][e1s] = r_z1;               \
    *(float4*)&s_bc[buf][t << 2] = r_bc;                                  \
  } while (0)

  LOADC(0);
  STOREC(0);
  LOADC(1);
  __syncthreads();

  float h = 0.0f;
  for (int c = 0; c < NCH; ++c) {
    const int p = c & 1;
    #pragma unroll
    for (int st = 0; st < CHT; ++st) {
      const float dt = s_dt[p][g][st];
      const float u = s_u[p][g][st];
      const float Bn = s_bc[p][st * 32 + lane];
      const float Cn = s_bc[p][st * 32 + 16 + lane];
      const float dA = __expf(dt * An);
      h = fmaf(h, dA, dt * u * Bn);
      float pr = h * Cn;
      pr += __shfl_xor(pr, 1, 16);
      pr += __shfl_xor(pr, 2, 16);
      pr += __shfl_xor(pr, 4, 16);
      pr += __shfl_xor(pr, 8, 16);
      if (lane == 0) s_y[p][g][st] = pr + Dv * u;
    }
    __syncthreads();
    if (c + 1 < NCH) {
      STOREC(1 - p);
      if (c + 2 < NCH) LOADC(c + 2);
    }
    // writeback chunk c (gate with silu(z))
    {
      const int l0 = c << 5;
      const float z0 = s_z[p][e0g][e0s], z1 = s_z[p][e1g][e1s];
      const float v0 = s_y[p][e0g][e0s] * (z0 * sigmoidf_(z0));
      const float v1 = s_y[p][e1g][e1s] * (z1 * sigmoidf_(z1));
      const int lo0 = dir ? (SEQ - 1 - (l0 + e0s)) : (l0 + e0s);
      const int lo1 = dir ? (SEQ - 1 - (l0 + e1s)) : (l0 + e1s);
      ypB[row0 + lo0] = v0;
      ypB[row1 + lo1] = v1;
    }
    __syncthreads();
  }
  #undef LOADC
  #undef STOREC
}

extern "C" void kernel_launch(void* const* d_in, const int* in_sizes, int n_in,
                              void* d_out, int out_size, void* d_ws, size_t ws_size,
                              hipStream_t stream) {
  (void)in_sizes; (void)n_in; (void)out_size; (void)ws_size;
  const float* x       = (const float*)d_in[0];
  const float* norm_w  = (const float*)d_in[1];
  const float* in_proj = (const float*)d_in[2];
  const float* convw_f = (const float*)d_in[3];
  const float* convb_f = (const float*)d_in[4];
  const float* xpw_f   = (const float*)d_in[5];
  const float* dtw_f   = (const float*)d_in[6];
  const float* dtb_f   = (const float*)d_in[7];
  const float* Alog_f  = (const float*)d_in[8];
  const float* Dsk_f   = (const float*)d_in[9];
  const float* convw_r = (const float*)d_in[10];
  const float* convb_r = (const float*)d_in[11];
  const float* xpw_r   = (const float*)d_in[12];
  const float* dtw_r   = (const float*)d_in[13];
  const float* dtb_r   = (const float*)d_in[14];
  const float* Alog_r  = (const float*)d_in[15];
  const float* Dsk_r   = (const float*)d_in[16];
  const float* out_w   = (const float*)d_in[17];
  const float* normf_w = (const float*)d_in[18];

  float* ws = (float*)d_ws;
  float* residual = ws;  ws += 524288;
  float* hn       = ws;  ws += 524288;
  float* xzbuf    = ws;  ws += 2097152;
  float* xconv_f  = ws;  ws += 1048576;
  float* xconv_r  = ws;  ws += 1048576;
  float* xdbl_f   = ws;  ws += 32768;
  float* xdbl_r   = ws;  ws += 32768;
  float* xbc_f    = ws;  ws += 32768;
  float* xbc_r    = ws;  ws += 32768;
  float* delta_f  = ws;  ws += 1048576;
  float* delta_r  = ws;  ws += 1048576;
  float* y_f      = ws;  ws += 1048576;
  float* y_r      = ws;  ws += 1048576;
  float* hs       = ws;  ws += 524288;

  float* outp = (float*)d_out;

  for (int layer = 0; layer < 4; ++layer) {
    addnorm_kernel<<<1024, 256, 0, stream>>>(
        layer == 0 ? x : hs, residual, norm_w + layer * DMODEL, hn, layer == 0 ? 1 : 0);
    gemm64_kernel<<<dim3(16, 32), 256, 0, stream>>>(
        in_proj + (long)layer * 2048 * 512, hn, nullptr, xzbuf, nullptr,
        2048, 1024, 512, 1024, 1, 1);
    conv_silu_kernel<<<dim3(4096, 2), 256, 0, stream>>>(
        xzbuf, convw_f + layer * DINNER * 4, convb_f + layer * DINNER,
        convw_r + layer * DINNER * 4, convb_r + layer * DINNER, xconv_f, xconv_r);
    xdbl_kernel<<<dim3(64, 2), 256, 0, stream>>>(
        xconv_f, xconv_r, xpw_f + layer * 64 * DINNER, xpw_r + layer * 64 * DINNER,
        xdbl_f, xdbl_r, xbc_f, xbc_r);
    delta_kernel<<<dim3(1024, 2), 256, 0, stream>>>(
        xdbl_f, xdbl_r, dtw_f + layer * DINNER * DTRANK, dtw_r + layer * DINNER * DTRANK,
        dtb_f + layer * DINNER, dtb_r + layer * DINNER, delta_f, delta_r);
    scan_kernel<<<256, 256, 0, stream>>>(
        xzbuf, xconv_f, xconv_r, delta_f, delta_r, xbc_f, xbc_r,
        Alog_f + layer * DINNER * DSTATE, Alog_r + layer * DINNER * DSTATE,
        Dsk_f + layer * DINNER, Dsk_r + layer * DINNER, y_f, y_r);
    gemm64_kernel<<<dim3(16, 8), 256, 0, stream>>>(
        out_w + (long)layer * 512 * 1024, y_f, y_r, hs,
        outp + (long)(1 + layer) * 524288,
        512, 1024, 1024, 1, 512, 0);
  }
  addnorm_kernel<<<1024, 256, 0, stream>>>(hs, residual, normf_w, outp, 0);
}

// Round 3
// 987.202 us; speedup vs baseline: 2.0262x; 1.4376x over previous
//
#include <hip/hip_runtime.h>

#define BATCH 2
#define SEQ 512
#define DMODEL 512
#define DINNER 1024
#define DSTATE 16
#define DTRANK 32
#define NBL (BATCH*SEQ)      // 1024
#define EPSV 1e-5f

typedef __attribute__((ext_vector_type(8))) short bf16x8;
typedef __attribute__((ext_vector_type(4))) float f32x4;

static __device__ __forceinline__ float sigmoidf_(float x) {
  return 1.0f / (1.0f + __expf(-x));
}
static __device__ __forceinline__ float softplusf_(float x) {
  return fmaxf(x, 0.0f) + log1pf(__expf(-fabsf(x)));
}
static __device__ __forceinline__ unsigned short f2bf(float x) {
  unsigned int u = __float_as_uint(x);
  unsigned int r = (u + 0x7FFFu + ((u >> 16) & 1u)) >> 16;
  return (unsigned short)r;
}

// ---------------- fp32 -> bf16 convert (weights) ----------------
__global__ __launch_bounds__(256) void tobf16_kernel(
    const float* __restrict__ in, unsigned short* __restrict__ out, int n) {
  const int i = (blockIdx.x * 256 + threadIdx.x) * 8;
  if (i >= n) return;
  const float4 v0 = *(const float4*)&in[i];
  const float4 v1 = *(const float4*)&in[i + 4];
  bf16x8 o;
  o[0] = (short)f2bf(v0.x); o[1] = (short)f2bf(v0.y);
  o[2] = (short)f2bf(v0.z); o[3] = (short)f2bf(v0.w);
  o[4] = (short)f2bf(v1.x); o[5] = (short)f2bf(v1.y);
  o[6] = (short)f2bf(v1.z); o[7] = (short)f2bf(v1.w);
  *(bf16x8*)&out[i] = o;
}

// ---------------- fused add + RMSNorm (fp32 and/or bf16 out) ----------------
__global__ __launch_bounds__(256) void addnorm_kernel(
    const float* __restrict__ hs, float* __restrict__ residual,
    const float* __restrict__ w, float* __restrict__ out,
    unsigned short* __restrict__ outb, int first) {
  const int row = blockIdx.x;
  const int t = threadIdx.x;
  const float* hp = hs + (long)row * DMODEL;
  float* rp = residual + (long)row * DMODEL;
  float r0 = hp[t], r1 = hp[t + 256];
  if (!first) { r0 += rp[t]; r1 += rp[t + 256]; }
  rp[t] = r0; rp[t + 256] = r1;
  float ss = r0 * r0 + r1 * r1;
  #pragma unroll
  for (int off = 32; off; off >>= 1) ss += __shfl_xor(ss, off, 64);
  __shared__ float sw[4];
  const int wid = t >> 6, lane = t & 63;
  if (lane == 0) sw[wid] = ss;
  __syncthreads();
  const float tot = sw[0] + sw[1] + sw[2] + sw[3];
  const float scale = rsqrtf(tot * (1.0f / (float)DMODEL) + EPSV);
  const float v0 = r0 * scale * w[t];
  const float v1 = r1 * scale * w[t + 256];
  if (out) {
    out[(long)row * DMODEL + t] = v0;
    out[(long)row * DMODEL + t + 256] = v1;
  }
  if (outb) {
    outb[(long)row * DMODEL + t] = f2bf(v0);
    outb[(long)row * DMODEL + t + 256] = f2bf(v1);
  }
}

// ---------------- bf16 MFMA GEMM, 128x128 tile ----------------
// A: (M,K) row-major bf16; B: (N,K) row-major bf16 (both K-contiguous).
// C[m,n] stored at m*ldm + n*ldn (fp32), optional duplicate C2.
// Grid: (N/128, M/128). Block 256 = 4 waves (2x2 of 64x64 each).
#define LDK 40
__global__ __launch_bounds__(256) void gemm_mfma_kernel(
    const unsigned short* __restrict__ A, const unsigned short* __restrict__ B,
    float* __restrict__ C, float* __restrict__ C2,
    int K, int ldm, int ldn) {
  __shared__ unsigned short As[128 * LDK];
  __shared__ unsigned short Bs[128 * LDK];
  const int t = threadIdx.x;
  const int m0 = blockIdx.y * 128, n0 = blockIdx.x * 128;
  const int lane = t & 63;
  const int w = t >> 6;
  const int wr = (w >> 1) * 64, wc = (w & 1) * 64;
  const int fr = lane & 15;   // fragment row/col
  const int fq = lane >> 4;   // k-quad (0..3)

  f32x4 acc[4][4];
  #pragma unroll
  for (int i = 0; i < 4; ++i)
    #pragma unroll
    for (int j = 0; j < 4; ++j) {
      f32x4 z = {0.f, 0.f, 0.f, 0.f};
      acc[i][j] = z;
    }

  const int srow = t >> 1;         // 0..127
  const int sko = (t & 1) * 16;    // 0 or 16

  for (int k0 = 0; k0 < K; k0 += 32) {
    if (k0) __syncthreads();
    *(bf16x8*)&As[srow * LDK + sko] =
        *(const bf16x8*)&A[(long)(m0 + srow) * K + k0 + sko];
    *(bf16x8*)&As[srow * LDK + sko + 8] =
        *(const bf16x8*)&A[(long)(m0 + srow) * K + k0 + sko + 8];
    *(bf16x8*)&Bs[srow * LDK + sko] =
        *(const bf16x8*)&B[(long)(n0 + srow) * K + k0 + sko];
    *(bf16x8*)&Bs[srow * LDK + sko + 8] =
        *(const bf16x8*)&B[(long)(n0 + srow) * K + k0 + sko + 8];
    __syncthreads();
    bf16x8 af[4], bg[4];
    #pragma unroll
    for (int i = 0; i < 4; ++i) {
      af[i] = *(const bf16x8*)&As[(wr + i * 16 + fr) * LDK + fq * 8];
      bg[i] = *(const bf16x8*)&Bs[(wc + i * 16 + fr) * LDK + fq * 8];
    }
    #pragma unroll
    for (int i = 0; i < 4; ++i)
      #pragma unroll
      for (int j = 0; j < 4; ++j)
        acc[i][j] = __builtin_amdgcn_mfma_f32_16x16x32_bf16(
            af[i], bg[j], acc[i][j], 0, 0, 0);
  }

  #pragma unroll
  for (int i = 0; i < 4; ++i)
    #pragma unroll
    for (int j = 0; j < 4; ++j)
      #pragma unroll
      for (int r2 = 0; r2 < 4; ++r2) {
        const int m = m0 + wr + i * 16 + fq * 4 + r2;
        const int n = n0 + wc + j * 16 + fr;
        const long addr = (long)m * ldm + (long)n * ldn;
        C[addr] = acc[i][j][r2];
        if (C2) C2[addr] = acc[i][j][r2];
      }
}

// ---------------- depthwise causal conv (K=4) + SiLU, both dirs ----------------
__global__ __launch_bounds__(256) void conv_silu_kernel(
    const float* __restrict__ xz,
    const float* __restrict__ cw_f, const float* __restrict__ cb_f,
    const float* __restrict__ cw_r, const float* __restrict__ cb_r,
    float* __restrict__ xconv_f, float* __restrict__ xconv_r) {
  const int dir = blockIdx.y;
  const int idx = blockIdx.x * 256 + threadIdx.x;
  const int l = idx & (SEQ - 1);
  const int bd = idx >> 9;
  const int b = bd & 1, d = bd >> 1;
  const float* cw = dir ? cw_r : cw_f;
  const float* cb = dir ? cb_r : cb_f;
  const float* xi = xz + (long)d * NBL + b * SEQ;
  float sum = cb[d];
  #pragma unroll
  for (int k = 0; k < 4; ++k) {
    const int tt = l - 3 + k;
    if (tt >= 0) {
      const int src = dir ? (SEQ - 1 - tt) : tt;
      sum += cw[d * 4 + k] * xi[src];
    }
  }
  const float v = sum * sigmoidf_(sum);
  (dir ? xconv_r : xconv_f)[idx] = v;
}

// ---------------- x_dbl = xpw @ xconv ----------------
__global__ __launch_bounds__(256) void xdbl_kernel(
    const float* __restrict__ xconv_f, const float* __restrict__ xconv_r,
    const float* __restrict__ xpw_f, const float* __restrict__ xpw_r,
    float* __restrict__ xdbl_f, float* __restrict__ xdbl_r,
    float* __restrict__ xbc_f, float* __restrict__ xbc_r) {
  const int dir = blockIdx.y;
  const int idx = blockIdx.x * 256 + threadIdx.x;
  const int n = idx & (NBL - 1);
  const int rg = idx >> 10;  // 0..15
  const float* xc = dir ? xconv_r : xconv_f;
  const float* xpw = dir ? xpw_r : xpw_f;
  float a0 = 0.f, a1 = 0.f, a2 = 0.f, a3 = 0.f;
  #pragma unroll 8
  for (int e = 0; e < DINNER; ++e) {
    const float xv = xc[(long)e * NBL + n];
    a0 = fmaf(xpw[(rg) * DINNER + e], xv, a0);
    a1 = fmaf(xpw[(rg + 16) * DINNER + e], xv, a1);
    a2 = fmaf(xpw[(rg + 32) * DINNER + e], xv, a2);
    a3 = fmaf(xpw[(rg + 48) * DINNER + e], xv, a3);
  }
  float* xd = dir ? xdbl_r : xdbl_f;
  float* xbc = dir ? xbc_r : xbc_f;
  xd[(long)(rg) * NBL + n] = a0;
  xd[(long)(rg + 16) * NBL + n] = a1;
  xbc[(long)n * 32 + rg] = a2;
  xbc[(long)n * 32 + 16 + rg] = a3;
}

// ---------------- delta = softplus(dtw @ dt + dtb) ----------------
__global__ __launch_bounds__(256) void delta_kernel(
    const float* __restrict__ xdbl_f, const float* __restrict__ xdbl_r,
    const float* __restrict__ dtw_f, const float* __restrict__ dtw_r,
    const float* __restrict__ dtb_f, const float* __restrict__ dtb_r,
    float* __restrict__ delta_f, float* __restrict__ delta_r) {
  const int dir = blockIdx.y;
  const int idx = blockIdx.x * 256 + threadIdx.x;
  const int n = idx & (NBL - 1);
  const int dg = idx >> 10;  // 0..255
  const float* xd = dir ? xdbl_r : xdbl_f;
  const float* dtw = dir ? dtw_r : dtw_f;
  const float* dtb = dir ? dtb_r : dtb_f;
  float acc[4];
  #pragma unroll
  for (int j = 0; j < 4; ++j) acc[j] = dtb[dg + 256 * j];
  #pragma unroll
  for (int r = 0; r < DTRANK; ++r) {
    const float xv = xd[(long)r * NBL + n];
    #pragma unroll
    for (int j = 0; j < 4; ++j)
      acc[j] = fmaf(dtw[(dg + 256 * j) * DTRANK + r], xv, acc[j]);
  }
  float* dl = dir ? delta_r : delta_f;
  #pragma unroll
  for (int j = 0; j < 4; ++j)
    dl[(long)(dg + 256 * j) * NBL + n] = softplusf_(acc[j]);
}

// ---------------- selective scan, LDS-staged + prefetch ----------------
#define CHT 32
#define NCH (SEQ / CHT)
__global__ __launch_bounds__(256) void scan_kernel(
    const float* __restrict__ xz,
    const float* __restrict__ xconv_f, const float* __restrict__ xconv_r,
    const float* __restrict__ delta_f, const float* __restrict__ delta_r,
    const float* __restrict__ xbc_f, const float* __restrict__ xbc_r,
    const float* __restrict__ Alog_f, const float* __restrict__ Alog_r,
    const float* __restrict__ Dsk_f, const float* __restrict__ Dsk_r,
    float* __restrict__ y_f, float* __restrict__ y_r) {
  __shared__ float s_dt[2][16][CHT + 1];
  __shared__ float s_u[2][16][CHT + 1];
  __shared__ float s_z[2][16][CHT + 1];
  __shared__ float s_y[2][16][CHT + 1];
  __shared__ float s_bc[2][CHT * 32];

  const int t = threadIdx.x;
  const int bx = blockIdx.x;
  const int dir = bx >> 7;
  const int b = (bx >> 6) & 1;
  const int d0 = (bx & 63) << 4;
  const int g = t >> 4;
  const int lane = t & 15;

  const float* dpB = (dir ? delta_r : delta_f);
  const float* upB = (dir ? xconv_r : xconv_f);
  const float* bcB = (dir ? xbc_r : xbc_f) + (long)b * SEQ * 32;
  const float* Alog = dir ? Alog_r : Alog_f;
  const float* Dsk = dir ? Dsk_r : Dsk_f;
  float* ypB = (dir ? y_r : y_f);

  const int d = d0 + g;
  const float An = -__expf(Alog[d * DSTATE + lane]);
  const float Dv = Dsk[d];

  const int e0g = t >> 5, e0s = t & 31;
  const int e1g = (t + 256) >> 5, e1s = t & 31;
  const long row0 = (long)(d0 + e0g) * NBL + b * SEQ;
  const long row1 = (long)(d0 + e1g) * NBL + b * SEQ;
  const long zrow0 = (long)(DINNER + d0 + e0g) * NBL + b * SEQ;
  const long zrow1 = (long)(DINNER + d0 + e1g) * NBL + b * SEQ;

  float r_dt0, r_dt1, r_u0, r_u1, r_z0, r_z1;
  float4 r_bc;

  #define LOADC(c) do {                                                   \
    const int l0_ = (c) << 5;                                             \
    r_dt0 = dpB[row0 + l0_ + e0s]; r_dt1 = dpB[row1 + l0_ + e1s];         \
    r_u0 = upB[row0 + l0_ + e0s];  r_u1 = upB[row1 + l0_ + e1s];          \
    const int lo0_ = dir ? (SEQ - 1 - (l0_ + e0s)) : (l0_ + e0s);         \
    const int lo1_ = dir ? (SEQ - 1 - (l0_ + e1s)) : (l0_ + e1s);         \
    r_z0 = xz[zrow0 + lo0_]; r_z1 = xz[zrow1 + lo1_];                     \
    r_bc = *(const float4*)&bcB[(l0_ << 5) + (t << 2)];                   \
  } while (0)

  #define STOREC(buf) do {                                                \
    s_dt[buf][e0g][e0s] = r_dt0; s_dt[buf][e1g][e1s] = r_dt1;             \
    s_u[buf][e0g][e0s] = r_u0;   s_u[buf][e1g][e1s] = r_u1;               \
    s_z[buf][e0g][e0s] = r_z0;   s_z[buf][e1g][e1s] = r_z1;               \
    *(float4*)&s_bc[buf][t << 2] = r_bc;                                  \
  } while (0)

  LOADC(0);
  STOREC(0);
  LOADC(1);
  __syncthreads();

  float h = 0.0f;
  for (int c = 0; c < NCH; ++c) {
    const int p = c & 1;
    #pragma unroll
    for (int st = 0; st < CHT; ++st) {
      const float dt = s_dt[p][g][st];
      const float u = s_u[p][g][st];
      const float Bn = s_bc[p][st * 32 + lane];
      const float Cn = s_bc[p][st * 32 + 16 + lane];
      const float dA = __expf(dt * An);
      h = fmaf(h, dA, dt * u * Bn);
      float pr = h * Cn;
      pr += __shfl_xor(pr, 1, 16);
      pr += __shfl_xor(pr, 2, 16);
      pr += __shfl_xor(pr, 4, 16);
      pr += __shfl_xor(pr, 8, 16);
      if (lane == 0) s_y[p][g][st] = pr + Dv * u;
    }
    __syncthreads();
    if (c + 1 < NCH) {
      STOREC(1 - p);
      if (c + 2 < NCH) LOADC(c + 2);
    }
    {
      const int l0 = c << 5;
      const float z0 = s_z[p][e0g][e0s], z1 = s_z[p][e1g][e1s];
      const float v0 = s_y[p][e0g][e0s] * (z0 * sigmoidf_(z0));
      const float v1 = s_y[p][e1g][e1s] * (z1 * sigmoidf_(z1));
      const int lo0 = dir ? (SEQ - 1 - (l0 + e0s)) : (l0 + e0s);
      const int lo1 = dir ? (SEQ - 1 - (l0 + e1s)) : (l0 + e1s);
      ypB[row0 + lo0] = v0;
      ypB[row1 + lo1] = v1;
    }
    __syncthreads();
  }
  #undef LOADC
  #undef STOREC
}

// ---------------- y transpose + add + bf16: ybt[n][e] = yf[e][n]+yr[e][n] ----
__global__ __launch_bounds__(256) void ytrans_kernel(
    const float* __restrict__ yf, const float* __restrict__ yr,
    unsigned short* __restrict__ yt) {
  __shared__ unsigned short tile[32][33];
  const int e0 = blockIdx.y * 32, n0 = blockIdx.x * 32;
  const int t = threadIdx.x;
  const int c = t & 31, r8 = t >> 5;
  #pragma unroll
  for (int p = 0; p < 4; ++p) {
    const int e = e0 + p * 8 + r8;
    const float v = yf[(long)e * NBL + n0 + c] + yr[(long)e * NBL + n0 + c];
    tile[p * 8 + r8][c] = f2bf(v);
  }
  __syncthreads();
  #pragma unroll
  for (int p = 0; p < 4; ++p) {
    const int n = n0 + p * 8 + r8;
    yt[(long)n * DINNER + e0 + c] = tile[c][p * 8 + r8];
  }
}

extern "C" void kernel_launch(void* const* d_in, const int* in_sizes, int n_in,
                              void* d_out, int out_size, void* d_ws, size_t ws_size,
                              hipStream_t stream) {
  (void)in_sizes; (void)n_in; (void)out_size; (void)ws_size;
  const float* x       = (const float*)d_in[0];
  const float* norm_w  = (const float*)d_in[1];
  const float* in_proj = (const float*)d_in[2];
  const float* convw_f = (const float*)d_in[3];
  const float* convb_f = (const float*)d_in[4];
  const float* xpw_f   = (const float*)d_in[5];
  const float* dtw_f   = (const float*)d_in[6];
  const float* dtb_f   = (const float*)d_in[7];
  const float* Alog_f  = (const float*)d_in[8];
  const float* Dsk_f   = (const float*)d_in[9];
  const float* convw_r = (const float*)d_in[10];
  const float* convb_r = (const float*)d_in[11];
  const float* xpw_r   = (const float*)d_in[12];
  const float* dtw_r   = (const float*)d_in[13];
  const float* dtb_r   = (const float*)d_in[14];
  const float* Alog_r  = (const float*)d_in[15];
  const float* Dsk_r   = (const float*)d_in[16];
  const float* out_w   = (const float*)d_in[17];
  const float* normf_w = (const float*)d_in[18];

  float* ws = (float*)d_ws;
  float* residual = ws;  ws += 524288;
  float* ybt_f    = ws;  ws += 524288;   // 1024x1024 bf16 (y transposed)
  float* xzbuf    = ws;  ws += 2097152;
  float* xconv_f  = ws;  ws += 1048576;
  float* xconv_r  = ws;  ws += 1048576;
  float* xdbl_f   = ws;  ws += 32768;
  float* xdbl_r   = ws;  ws += 32768;
  float* xbc_f    = ws;  ws += 32768;
  float* xbc_r    = ws;  ws += 32768;
  float* delta_f  = ws;  ws += 1048576;
  float* delta_r  = ws;  ws += 1048576;
  float* y_f      = ws;  ws += 1048576;
  float* y_r      = ws;  ws += 1048576;
  float* hs       = ws;  ws += 524288;
  float* hnb_f    = ws;  ws += 262144;   // 1024x512 bf16 (hn)
  float* wconv_f  = ws;  ws += 524288;   // up to 2048x512 bf16 (weights)

  unsigned short* ybt = (unsigned short*)ybt_f;
  unsigned short* hnb = (unsigned short*)hnb_f;
  unsigned short* wconv = (unsigned short*)wconv_f;

  float* outp = (float*)d_out;

  for (int layer = 0; layer < 4; ++layer) {
    addnorm_kernel<<<1024, 256, 0, stream>>>(
        layer == 0 ? x : hs, residual, norm_w + layer * DMODEL,
        nullptr, hnb, layer == 0 ? 1 : 0);
    // in_proj weight -> bf16, then MFMA GEMM: xz = W (2048x512) @ hn^T
    tobf16_kernel<<<512, 256, 0, stream>>>(
        in_proj + (long)layer * 2048 * 512, wconv, 2048 * 512);
    gemm_mfma_kernel<<<dim3(8, 16), 256, 0, stream>>>(
        wconv, hnb, xzbuf, nullptr, 512, 1024, 1);
    conv_silu_kernel<<<dim3(4096, 2), 256, 0, stream>>>(
        xzbuf, convw_f + layer * DINNER * 4, convb_f + layer * DINNER,
        convw_r + layer * DINNER * 4, convb_r + layer * DINNER, xconv_f, xconv_r);
    xdbl_kernel<<<dim3(64, 2), 256, 0, stream>>>(
        xconv_f, xconv_r, xpw_f + layer * 64 * DINNER, xpw_r + layer * 64 * DINNER,
        xdbl_f, xdbl_r, xbc_f, xbc_r);
    delta_kernel<<<dim3(1024, 2), 256, 0, stream>>>(
        xdbl_f, xdbl_r, dtw_f + layer * DINNER * DTRANK, dtw_r + layer * DINNER * DTRANK,
        dtb_f + layer * DINNER, dtb_r + layer * DINNER, delta_f, delta_r);
    scan_kernel<<<256, 256, 0, stream>>>(
        xzbuf, xconv_f, xconv_r, delta_f, delta_r, xbc_f, xbc_r,
        Alog_f + layer * DINNER * DSTATE, Alog_r + layer * DINNER * DSTATE,
        Dsk_f + layer * DINNER, Dsk_r + layer * DINNER, y_f, y_r);
    // y_f + y_r -> transposed bf16 (n, e)
    ytrans_kernel<<<dim3(32, 32), 256, 0, stream>>>(y_f, y_r, ybt);
    // out_proj weight -> bf16, then MFMA GEMM: hs[n,d] = out_w (512x1024) @ ybt^T
    tobf16_kernel<<<256, 256, 0, stream>>>(
        out_w + (long)layer * 512 * 1024, wconv, 512 * 1024);
    gemm_mfma_kernel<<<dim3(8, 4), 256, 0, stream>>>(
        wconv, ybt, hs, outp + (long)(1 + layer) * 524288,
        1024, 1, 512);
  }
  addnorm_kernel<<<1024, 256, 0, stream>>>(hs, residual, normf_w, outp, nullptr, 0);
}

// Round 4
// 737.843 us; speedup vs baseline: 2.7110x; 1.3380x over previous
//
#include <hip/hip_runtime.h>

#define BATCH 2
#define SEQ 512
#define DMODEL 512
#define DINNER 1024
#define DSTATE 16
#define DTRANK 32
#define NBL (BATCH*SEQ)      // 1024
#define EPSV 1e-5f

typedef __attribute__((ext_vector_type(8))) short bf16x8;
typedef __attribute__((ext_vector_type(4))) float f32x4;

static __device__ __forceinline__ float sigmoidf_(float x) {
  return 1.0f / (1.0f + __expf(-x));
}
static __device__ __forceinline__ float softplusf_(float x) {
  return fmaxf(x, 0.0f) + log1pf(__expf(-fabsf(x)));
}
static __device__ __forceinline__ unsigned short f2bf(float x) {
  unsigned int u = __float_as_uint(x);
  unsigned int r = (u + 0x7FFFu + ((u >> 16) & 1u)) >> 16;
  return (unsigned short)r;
}

// row_shr DPP add within 16-lane rows (full-rate VALU cross-lane)
#define DPPADD(v, ctrl)                                                     \
  v += __int_as_float(__builtin_amdgcn_update_dpp(                          \
      0, __float_as_int(v), ctrl, 0xf, 0xf, true))

// ---------------- fp32 -> bf16 convert (weights) ----------------
__global__ __launch_bounds__(256) void tobf16_kernel(
    const float* __restrict__ in, unsigned short* __restrict__ out, int n) {
  const int i = (blockIdx.x * 256 + threadIdx.x) * 8;
  if (i >= n) return;
  const float4 v0 = *(const float4*)&in[i];
  const float4 v1 = *(const float4*)&in[i + 4];
  bf16x8 o;
  o[0] = (short)f2bf(v0.x); o[1] = (short)f2bf(v0.y);
  o[2] = (short)f2bf(v0.z); o[3] = (short)f2bf(v0.w);
  o[4] = (short)f2bf(v1.x); o[5] = (short)f2bf(v1.y);
  o[6] = (short)f2bf(v1.z); o[7] = (short)f2bf(v1.w);
  *(bf16x8*)&out[i] = o;
}

// ---------------- fused add + RMSNorm (fp32 and/or bf16 out) ----------------
__global__ __launch_bounds__(256) void addnorm_kernel(
    const float* __restrict__ hs, float* __restrict__ residual,
    const float* __restrict__ w, float* __restrict__ out,
    unsigned short* __restrict__ outb, int first) {
  const int row = blockIdx.x;
  const int t = threadIdx.x;
  const float* hp = hs + (long)row * DMODEL;
  float* rp = residual + (long)row * DMODEL;
  float r0 = hp[t], r1 = hp[t + 256];
  if (!first) { r0 += rp[t]; r1 += rp[t + 256]; }
  rp[t] = r0; rp[t + 256] = r1;
  float ss = r0 * r0 + r1 * r1;
  #pragma unroll
  for (int off = 32; off; off >>= 1) ss += __shfl_xor(ss, off, 64);
  __shared__ float sw[4];
  const int wid = t >> 6, lane = t & 63;
  if (lane == 0) sw[wid] = ss;
  __syncthreads();
  const float tot = sw[0] + sw[1] + sw[2] + sw[3];
  const float scale = rsqrtf(tot * (1.0f / (float)DMODEL) + EPSV);
  const float v0 = r0 * scale * w[t];
  const float v1 = r1 * scale * w[t + 256];
  if (out) {
    out[(long)row * DMODEL + t] = v0;
    out[(long)row * DMODEL + t + 256] = v1;
  }
  if (outb) {
    outb[(long)row * DMODEL + t] = f2bf(v0);
    outb[(long)row * DMODEL + t + 256] = f2bf(v1);
  }
}

// ---------------- bf16 MFMA GEMM, 128x128 tile ----------------
#define LDK 40
__global__ __launch_bounds__(256) void gemm_mfma_kernel(
    const unsigned short* __restrict__ A, const unsigned short* __restrict__ B,
    float* __restrict__ C, float* __restrict__ C2,
    int K, int ldm, int ldn) {
  __shared__ unsigned short As[128 * LDK];
  __shared__ unsigned short Bs[128 * LDK];
  const int t = threadIdx.x;
  const int m0 = blockIdx.y * 128, n0 = blockIdx.x * 128;
  const int lane = t & 63;
  const int w = t >> 6;
  const int wr = (w >> 1) * 64, wc = (w & 1) * 64;
  const int fr = lane & 15;
  const int fq = lane >> 4;

  f32x4 acc[4][4];
  #pragma unroll
  for (int i = 0; i < 4; ++i)
    #pragma unroll
    for (int j = 0; j < 4; ++j) {
      f32x4 z = {0.f, 0.f, 0.f, 0.f};
      acc[i][j] = z;
    }

  const int srow = t >> 1;
  const int sko = (t & 1) * 16;

  for (int k0 = 0; k0 < K; k0 += 32) {
    if (k0) __syncthreads();
    *(bf16x8*)&As[srow * LDK + sko] =
        *(const bf16x8*)&A[(long)(m0 + srow) * K + k0 + sko];
    *(bf16x8*)&As[srow * LDK + sko + 8] =
        *(const bf16x8*)&A[(long)(m0 + srow) * K + k0 + sko + 8];
    *(bf16x8*)&Bs[srow * LDK + sko] =
        *(const bf16x8*)&B[(long)(n0 + srow) * K + k0 + sko];
    *(bf16x8*)&Bs[srow * LDK + sko + 8] =
        *(const bf16x8*)&B[(long)(n0 + srow) * K + k0 + sko + 8];
    __syncthreads();
    bf16x8 af[4], bg[4];
    #pragma unroll
    for (int i = 0; i < 4; ++i) {
      af[i] = *(const bf16x8*)&As[(wr + i * 16 + fr) * LDK + fq * 8];
      bg[i] = *(const bf16x8*)&Bs[(wc + i * 16 + fr) * LDK + fq * 8];
    }
    #pragma unroll
    for (int i = 0; i < 4; ++i)
      #pragma unroll
      for (int j = 0; j < 4; ++j)
        acc[i][j] = __builtin_amdgcn_mfma_f32_16x16x32_bf16(
            af[i], bg[j], acc[i][j], 0, 0, 0);
  }

  #pragma unroll
  for (int i = 0; i < 4; ++i)
    #pragma unroll
    for (int j = 0; j < 4; ++j)
      #pragma unroll
      for (int r2 = 0; r2 < 4; ++r2) {
        const int m = m0 + wr + i * 16 + fq * 4 + r2;
        const int n = n0 + wc + j * 16 + fr;
        const long addr = (long)m * ldm + (long)n * ldn;
        C[addr] = acc[i][j][r2];
        if (C2) C2[addr] = acc[i][j][r2];
      }
}

// ---------------- depthwise causal conv (K=4) + SiLU, both dirs ----------------
__global__ __launch_bounds__(256) void conv_silu_kernel(
    const float* __restrict__ xz,
    const float* __restrict__ cw_f, const float* __restrict__ cb_f,
    const float* __restrict__ cw_r, const float* __restrict__ cb_r,
    float* __restrict__ xconv_f, float* __restrict__ xconv_r) {
  const int dir = blockIdx.y;
  const int idx = blockIdx.x * 256 + threadIdx.x;
  const int l = idx & (SEQ - 1);
  const int bd = idx >> 9;
  const int b = bd & 1, d = bd >> 1;
  const float* cw = dir ? cw_r : cw_f;
  const float* cb = dir ? cb_r : cb_f;
  const float* xi = xz + (long)d * NBL + b * SEQ;
  float sum = cb[d];
  #pragma unroll
  for (int k = 0; k < 4; ++k) {
    const int tt = l - 3 + k;
    if (tt >= 0) {
      const int src = dir ? (SEQ - 1 - tt) : tt;
      sum += cw[d * 4 + k] * xi[src];
    }
  }
  const float v = sum * sigmoidf_(sum);
  (dir ? xconv_r : xconv_f)[idx] = v;
}

// ---------------- x_dbl = xpw @ xconv ----------------
__global__ __launch_bounds__(256) void xdbl_kernel(
    const float* __restrict__ xconv_f, const float* __restrict__ xconv_r,
    const float* __restrict__ xpw_f, const float* __restrict__ xpw_r,
    float* __restrict__ xdbl_f, float* __restrict__ xdbl_r,
    float* __restrict__ xbc_f, float* __restrict__ xbc_r) {
  const int dir = blockIdx.y;
  const int idx = blockIdx.x * 256 + threadIdx.x;
  const int n = idx & (NBL - 1);
  const int rg = idx >> 10;  // 0..15
  const float* xc = dir ? xconv_r : xconv_f;
  const float* xpw = dir ? xpw_r : xpw_f;
  float a0 = 0.f, a1 = 0.f, a2 = 0.f, a3 = 0.f;
  #pragma unroll 8
  for (int e = 0; e < DINNER; ++e) {
    const float xv = xc[(long)e * NBL + n];
    a0 = fmaf(xpw[(rg) * DINNER + e], xv, a0);
    a1 = fmaf(xpw[(rg + 16) * DINNER + e], xv, a1);
    a2 = fmaf(xpw[(rg + 32) * DINNER + e], xv, a2);
    a3 = fmaf(xpw[(rg + 48) * DINNER + e], xv, a3);
  }
  float* xd = dir ? xdbl_r : xdbl_f;
  float* xbc = dir ? xbc_r : xbc_f;
  xd[(long)(rg) * NBL + n] = a0;
  xd[(long)(rg + 16) * NBL + n] = a1;
  xbc[(long)n * 32 + rg] = a2;
  xbc[(long)n * 32 + 16 + rg] = a3;
}

// ---------------- delta = softplus(dtw @ dt + dtb) ----------------
__global__ __launch_bounds__(256) void delta_kernel(
    const float* __restrict__ xdbl_f, const float* __restrict__ xdbl_r,
    const float* __restrict__ dtw_f, const float* __restrict__ dtw_r,
    const float* __restrict__ dtb_f, const float* __restrict__ dtb_r,
    float* __restrict__ delta_f, float* __restrict__ delta_r) {
  const int dir = blockIdx.y;
  const int idx = blockIdx.x * 256 + threadIdx.x;
  const int n = idx & (NBL - 1);
  const int dg = idx >> 10;  // 0..255
  const float* xd = dir ? xdbl_r : xdbl_f;
  const float* dtw = dir ? dtw_r : dtw_f;
  const float* dtb = dir ? dtb_r : dtb_f;
  float acc[4];
  #pragma unroll
  for (int j = 0; j < 4; ++j) acc[j] = dtb[dg + 256 * j];
  #pragma unroll
  for (int r = 0; r < DTRANK; ++r) {
    const float xv = xd[(long)r * NBL + n];
    #pragma unroll
    for (int j = 0; j < 4; ++j)
      acc[j] = fmaf(dtw[(dg + 256 * j) * DTRANK + r], xv, acc[j]);
  }
  float* dl = dir ? delta_r : delta_f;
  #pragma unroll
  for (int j = 0; j < 4; ++j)
    dl[(long)(dg + 256 * j) * NBL + n] = softplusf_(acc[j]);
}

// ---------------- chunked selective scan ----------------
// rows R = dir*2048 + b*1024 + d  (4096 rows), 8 chunks of 64 steps.
// Pass A: per (row, chunk) with h0=0, compute local end-state hloc and
// per-state decay product Aprod. Pass B: compose true h0 from chunks < c,
// replay chunk, reduce y via DPP, gated coalesced writeback.
#define NCHK 8
#define CLEN 64
__global__ __launch_bounds__(256) void scan_partA(
    const float* __restrict__ delta_f, const float* __restrict__ delta_r,
    const float* __restrict__ xconv_f, const float* __restrict__ xconv_r,
    const float* __restrict__ xbc_f, const float* __restrict__ xbc_r,
    const float* __restrict__ Alog_f, const float* __restrict__ Alog_r,
    float* __restrict__ hloc, float* __restrict__ aprd) {
  const int t = threadIdx.x;
  const int gid = blockIdx.x * 16 + (t >> 4);
  const int lane = t & 15;
  const int c = gid & (NCHK - 1);
  const int row = gid >> 3;
  const int dir = row >> 11, b = (row >> 10) & 1, d = row & 1023;
  const float* dp = (dir ? delta_r : delta_f) + (long)d * NBL + b * SEQ + c * CLEN;
  const float* up = (dir ? xconv_r : xconv_f) + (long)d * NBL + b * SEQ + c * CLEN;
  const float* bc = (dir ? xbc_r : xbc_f) + ((long)b * SEQ + c * CLEN) * 32;
  const float An = -__expf((dir ? Alog_r : Alog_f)[d * DSTATE + lane]);
  float h = 0.f, P = 1.f;
  #pragma unroll 8
  for (int l = 0; l < CLEN; ++l) {
    const float dt = dp[l], u = up[l];
    const float Bn = bc[l * 32 + lane];
    const float dA = __expf(dt * An);
    h = fmaf(h, dA, dt * u * Bn);
    P *= dA;
  }
  hloc[(long)gid * 16 + lane] = h;
  aprd[(long)gid * 16 + lane] = P;
}

__global__ __launch_bounds__(256) void scan_partB(
    const float* __restrict__ delta_f, const float* __restrict__ delta_r,
    const float* __restrict__ xconv_f, const float* __restrict__ xconv_r,
    const float* __restrict__ xbc_f, const float* __restrict__ xbc_r,
    const float* __restrict__ Alog_f, const float* __restrict__ Alog_r,
    const float* __restrict__ Dsk_f, const float* __restrict__ Dsk_r,
    const float* __restrict__ hloc, const float* __restrict__ aprd,
    const float* __restrict__ xz,
    float* __restrict__ y_f, float* __restrict__ y_r) {
  __shared__ float s_y[16][CLEN + 4];
  const int t = threadIdx.x;
  const int g = t >> 4;
  const int gid = blockIdx.x * 16 + g;
  const int lane = t & 15;
  const int c = gid & (NCHK - 1);
  const int row = gid >> 3;
  const int dir = row >> 11, b = (row >> 10) & 1, d = row & 1023;
  const float* dp = (dir ? delta_r : delta_f) + (long)d * NBL + b * SEQ + c * CLEN;
  const float* up = (dir ? xconv_r : xconv_f) + (long)d * NBL + b * SEQ + c * CLEN;
  const float* bc = (dir ? xbc_r : xbc_f) + ((long)b * SEQ + c * CLEN) * 32;
  const float An = -__expf((dir ? Alog_r : Alog_f)[d * DSTATE + lane]);
  const float Dv = (dir ? Dsk_r : Dsk_f)[d];

  // compose initial state from previous chunks
  float h = 0.f;
  const long base = (long)(gid & ~(NCHK - 1)) * 16 + lane;
  for (int j = 0; j < c; ++j)
    h = fmaf(h, aprd[base + j * 16], hloc[base + j * 16]);

  #pragma unroll 4
  for (int l = 0; l < CLEN; ++l) {
    const float dt = dp[l], u = up[l];
    const float Bn = bc[l * 32 + lane];
    const float Cn = bc[l * 32 + 16 + lane];
    const float dA = __expf(dt * An);
    h = fmaf(h, dA, dt * u * Bn);
    float pr = h * Cn;
    DPPADD(pr, 0x111);  // row_shr:1
    DPPADD(pr, 0x112);  // row_shr:2
    DPPADD(pr, 0x114);  // row_shr:4
    DPPADD(pr, 0x118);  // row_shr:8  -> lane0 of each 16-row has the sum
    if (lane == 0) s_y[g][l] = fmaf(Dv, u, pr);
  }

  // gated coalesced writeback (same-wave LDS, no barrier needed)
  const float* zp = xz + (long)(DINNER + d) * NBL + b * SEQ;
  float* yp = (dir ? y_r : y_f) + (long)d * NBL + b * SEQ;
  #pragma unroll
  for (int k = 0; k < 4; ++k) {
    const int l = (lane << 2) + k;
    const int lg = c * CLEN + l;
    const int lo = dir ? (SEQ - 1 - lg) : lg;
    const float z = zp[lo];
    yp[lo] = s_y[g][l] * (z * sigmoidf_(z));
  }
}

// ---------------- y transpose + add + bf16: ybt[n][e] = yf[e][n]+yr[e][n] ----
__global__ __launch_bounds__(256) void ytrans_kernel(
    const float* __restrict__ yf, const float* __restrict__ yr,
    unsigned short* __restrict__ yt) {
  __shared__ unsigned short tile[32][33];
  const int e0 = blockIdx.y * 32, n0 = blockIdx.x * 32;
  const int t = threadIdx.x;
  const int c = t & 31, r8 = t >> 5;
  #pragma unroll
  for (int p = 0; p < 4; ++p) {
    const int e = e0 + p * 8 + r8;
    const float v = yf[(long)e * NBL + n0 + c] + yr[(long)e * NBL + n0 + c];
    tile[p * 8 + r8][c] = f2bf(v);
  }
  __syncthreads();
  #pragma unroll
  for (int p = 0; p < 4; ++p) {
    const int n = n0 + p * 8 + r8;
    yt[(long)n * DINNER + e0 + c] = tile[c][p * 8 + r8];
  }
}

extern "C" void kernel_launch(void* const* d_in, const int* in_sizes, int n_in,
                              void* d_out, int out_size, void* d_ws, size_t ws_size,
                              hipStream_t stream) {
  (void)in_sizes; (void)n_in; (void)out_size; (void)ws_size;
  const float* x       = (const float*)d_in[0];
  const float* norm_w  = (const float*)d_in[1];
  const float* in_proj = (const float*)d_in[2];
  const float* convw_f = (const float*)d_in[3];
  const float* convb_f = (const float*)d_in[4];
  const float* xpw_f   = (const float*)d_in[5];
  const float* dtw_f   = (const float*)d_in[6];
  const float* dtb_f   = (const float*)d_in[7];
  const float* Alog_f  = (const float*)d_in[8];
  const float* Dsk_f   = (const float*)d_in[9];
  const float* convw_r = (const float*)d_in[10];
  const float* convb_r = (const float*)d_in[11];
  const float* xpw_r   = (const float*)d_in[12];
  const float* dtw_r   = (const float*)d_in[13];
  const float* dtb_r   = (const float*)d_in[14];
  const float* Alog_r  = (const float*)d_in[15];
  const float* Dsk_r   = (const float*)d_in[16];
  const float* out_w   = (const float*)d_in[17];
  const float* normf_w = (const float*)d_in[18];

  float* ws = (float*)d_ws;
  float* residual = ws;  ws += 524288;
  float* ybt_f    = ws;  ws += 524288;   // 1024x1024 bf16
  float* xzbuf    = ws;  ws += 2097152;
  float* xconv_f  = ws;  ws += 1048576;
  float* xconv_r  = ws;  ws += 1048576;
  float* xdbl_f   = ws;  ws += 32768;
  float* xdbl_r   = ws;  ws += 32768;
  float* xbc_f    = ws;  ws += 32768;
  float* xbc_r    = ws;  ws += 32768;
  float* delta_f  = ws;  ws += 1048576;
  float* delta_r  = ws;  ws += 1048576;
  float* y_f      = ws;  ws += 1048576;
  float* y_r      = ws;  ws += 1048576;
  float* hs       = ws;  ws += 524288;
  float* hnb_f    = ws;  ws += 262144;   // 1024x512 bf16
  float* wbfin_f  = ws;  ws += 2097152;  // 4x2048x512 bf16
  float* wbfout_f = ws;  ws += 1048576;  // 4x512x1024 bf16
  float* hloc     = ws;  ws += 524288;   // 32768 x 16
  float* aprd     = ws;  ws += 524288;

  unsigned short* ybt = (unsigned short*)ybt_f;
  unsigned short* hnb = (unsigned short*)hnb_f;
  unsigned short* wbfin = (unsigned short*)wbfin_f;
  unsigned short* wbfout = (unsigned short*)wbfout_f;

  float* outp = (float*)d_out;

  // all-layer weight conversion up front
  tobf16_kernel<<<2048, 256, 0, stream>>>(in_proj, wbfin, 4 * 2048 * 512);
  tobf16_kernel<<<1024, 256, 0, stream>>>(out_w, wbfout, 4 * 512 * 1024);

  for (int layer = 0; layer < 4; ++layer) {
    addnorm_kernel<<<1024, 256, 0, stream>>>(
        layer == 0 ? x : hs, residual, norm_w + layer * DMODEL,
        nullptr, hnb, layer == 0 ? 1 : 0);
    gemm_mfma_kernel<<<dim3(8, 16), 256, 0, stream>>>(
        wbfin + (long)layer * 2048 * 512, hnb, xzbuf, nullptr, 512, 1024, 1);
    conv_silu_kernel<<<dim3(4096, 2), 256, 0, stream>>>(
        xzbuf, convw_f + layer * DINNER * 4, convb_f + layer * DINNER,
        convw_r + layer * DINNER * 4, convb_r + layer * DINNER, xconv_f, xconv_r);
    xdbl_kernel<<<dim3(64, 2), 256, 0, stream>>>(
        xconv_f, xconv_r, xpw_f + layer * 64 * DINNER, xpw_r + layer * 64 * DINNER,
        xdbl_f, xdbl_r, xbc_f, xbc_r);
    delta_kernel<<<dim3(1024, 2), 256, 0, stream>>>(
        xdbl_f, xdbl_r, dtw_f + layer * DINNER * DTRANK, dtw_r + layer * DINNER * DTRANK,
        dtb_f + layer * DINNER, dtb_r + layer * DINNER, delta_f, delta_r);
    scan_partA<<<2048, 256, 0, stream>>>(
        delta_f, delta_r, xconv_f, xconv_r, xbc_f, xbc_r,
        Alog_f + layer * DINNER * DSTATE, Alog_r + layer * DINNER * DSTATE,
        hloc, aprd);
    scan_partB<<<2048, 256, 0, stream>>>(
        delta_f, delta_r, xconv_f, xconv_r, xbc_f, xbc_r,
        Alog_f + layer * DINNER * DSTATE, Alog_r + layer * DINNER * DSTATE,
        Dsk_f + layer * DINNER, Dsk_r + layer * DINNER,
        hloc, aprd, xzbuf, y_f, y_r);
    ytrans_kernel<<<dim3(32, 32), 256, 0, stream>>>(y_f, y_r, ybt);
    gemm_mfma_kernel<<<dim3(8, 4), 256, 0, stream>>>(
        wbfout + (long)layer * 512 * 1024, ybt, hs,
        outp + (long)(1 + layer) * 524288, 1024, 1, 512);
  }
  addnorm_kernel<<<1024, 256, 0, stream>>>(hs, residual, normf_w, outp, nullptr, 0);
}

// Round 5
// 613.179 us; speedup vs baseline: 3.2621x; 1.2033x over previous
//
#include <hip/hip_runtime.h>

#define BATCH 2
#define SEQ 512
#define DMODEL 512
#define DINNER 1024
#define DSTATE 16
#define DTRANK 32
#define NBL (BATCH*SEQ)      // 1024
#define EPSV 1e-5f

typedef __attribute__((ext_vector_type(8))) short bf16x8;
typedef __attribute__((ext_vector_type(4))) float f32x4;

static __device__ __forceinline__ float sigmoidf_(float x) {
  return 1.0f / (1.0f + __expf(-x));
}
static __device__ __forceinline__ float softplusf_(float x) {
  return fmaxf(x, 0.0f) + log1pf(__expf(-fabsf(x)));
}
static __device__ __forceinline__ unsigned short f2bf(float x) {
  unsigned int u = __float_as_uint(x);
  unsigned int r = (u + 0x7FFFu + ((u >> 16) & 1u)) >> 16;
  return (unsigned short)r;
}

#define DPPADD(v, ctrl)                                                     \
  v += __int_as_float(__builtin_amdgcn_update_dpp(                          \
      0, __float_as_int(v), ctrl, 0xf, 0xf, true))

// ---------------- fp32 -> bf16 convert ----------------
__global__ __launch_bounds__(256) void tobf16_kernel(
    const float* __restrict__ in, unsigned short* __restrict__ out, int n) {
  const int i = (blockIdx.x * 256 + threadIdx.x) * 8;
  if (i >= n) return;
  const float4 v0 = *(const float4*)&in[i];
  const float4 v1 = *(const float4*)&in[i + 4];
  bf16x8 o;
  o[0] = (short)f2bf(v0.x); o[1] = (short)f2bf(v0.y);
  o[2] = (short)f2bf(v0.z); o[3] = (short)f2bf(v0.w);
  o[4] = (short)f2bf(v1.x); o[5] = (short)f2bf(v1.y);
  o[6] = (short)f2bf(v1.z); o[7] = (short)f2bf(v1.w);
  *(bf16x8*)&out[i] = o;
}

// ---------------- fused add + RMSNorm ----------------
__global__ __launch_bounds__(256) void addnorm_kernel(
    const float* __restrict__ hs, float* __restrict__ residual,
    const float* __restrict__ w, float* __restrict__ out,
    unsigned short* __restrict__ outb, int first) {
  const int row = blockIdx.x;
  const int t = threadIdx.x;
  const float* hp = hs + (long)row * DMODEL;
  float* rp = residual + (long)row * DMODEL;
  float r0 = hp[t], r1 = hp[t + 256];
  if (!first) { r0 += rp[t]; r1 += rp[t + 256]; }
  rp[t] = r0; rp[t + 256] = r1;
  float ss = r0 * r0 + r1 * r1;
  #pragma unroll
  for (int off = 32; off; off >>= 1) ss += __shfl_xor(ss, off, 64);
  __shared__ float sw[4];
  const int wid = t >> 6, lane = t & 63;
  if (lane == 0) sw[wid] = ss;
  __syncthreads();
  const float tot = sw[0] + sw[1] + sw[2] + sw[3];
  const float scale = rsqrtf(tot * (1.0f / (float)DMODEL) + EPSV);
  const float v0 = r0 * scale * w[t];
  const float v1 = r1 * scale * w[t + 256];
  if (out) {
    out[(long)row * DMODEL + t] = v0;
    out[(long)row * DMODEL + t + 256] = v1;
  }
  if (outb) {
    outb[(long)row * DMODEL + t] = f2bf(v0);
    outb[(long)row * DMODEL + t + 256] = f2bf(v1);
  }
}

// ---------------- bf16 MFMA GEMM, 128x128 tile ----------------
#define LDK 40
__global__ __launch_bounds__(256) void gemm_mfma_kernel(
    const unsigned short* __restrict__ A, const unsigned short* __restrict__ B,
    float* __restrict__ C, float* __restrict__ C2,
    int K, int ldm, int ldn) {
  __shared__ unsigned short As[128 * LDK];
  __shared__ unsigned short Bs[128 * LDK];
  const int t = threadIdx.x;
  const int m0 = blockIdx.y * 128, n0 = blockIdx.x * 128;
  const int lane = t & 63;
  const int w = t >> 6;
  const int wr = (w >> 1) * 64, wc = (w & 1) * 64;
  const int fr = lane & 15;
  const int fq = lane >> 4;

  f32x4 acc[4][4];
  #pragma unroll
  for (int i = 0; i < 4; ++i)
    #pragma unroll
    for (int j = 0; j < 4; ++j) {
      f32x4 z = {0.f, 0.f, 0.f, 0.f};
      acc[i][j] = z;
    }

  const int srow = t >> 1;
  const int sko = (t & 1) * 16;

  for (int k0 = 0; k0 < K; k0 += 32) {
    if (k0) __syncthreads();
    *(bf16x8*)&As[srow * LDK + sko] =
        *(const bf16x8*)&A[(long)(m0 + srow) * K + k0 + sko];
    *(bf16x8*)&As[srow * LDK + sko + 8] =
        *(const bf16x8*)&A[(long)(m0 + srow) * K + k0 + sko + 8];
    *(bf16x8*)&Bs[srow * LDK + sko] =
        *(const bf16x8*)&B[(long)(n0 + srow) * K + k0 + sko];
    *(bf16x8*)&Bs[srow * LDK + sko + 8] =
        *(const bf16x8*)&B[(long)(n0 + srow) * K + k0 + sko + 8];
    __syncthreads();
    bf16x8 af[4], bg[4];
    #pragma unroll
    for (int i = 0; i < 4; ++i) {
      af[i] = *(const bf16x8*)&As[(wr + i * 16 + fr) * LDK + fq * 8];
      bg[i] = *(const bf16x8*)&Bs[(wc + i * 16 + fr) * LDK + fq * 8];
    }
    #pragma unroll
    for (int i = 0; i < 4; ++i)
      #pragma unroll
      for (int j = 0; j < 4; ++j)
        acc[i][j] = __builtin_amdgcn_mfma_f32_16x16x32_bf16(
            af[i], bg[j], acc[i][j], 0, 0, 0);
  }

  #pragma unroll
  for (int i = 0; i < 4; ++i)
    #pragma unroll
    for (int j = 0; j < 4; ++j)
      #pragma unroll
      for (int r2 = 0; r2 < 4; ++r2) {
        const int m = m0 + wr + i * 16 + fq * 4 + r2;
        const int n = n0 + wc + j * 16 + fr;
        const long addr = (long)m * ldm + (long)n * ldn;
        C[addr] = acc[i][j][r2];
        if (C2) C2[addr] = acc[i][j][r2];
      }
}

// ---------------- depthwise causal conv (K=4) + SiLU ----------------
__global__ __launch_bounds__(256) void conv_silu_kernel(
    const float* __restrict__ xz,
    const float* __restrict__ cw_f, const float* __restrict__ cb_f,
    const float* __restrict__ cw_r, const float* __restrict__ cb_r,
    float* __restrict__ xconv_f, float* __restrict__ xconv_r) {
  const int dir = blockIdx.y;
  const int idx = blockIdx.x * 256 + threadIdx.x;
  const int l = idx & (SEQ - 1);
  const int bd = idx >> 9;
  const int b = bd & 1, d = bd >> 1;
  const float* cw = dir ? cw_r : cw_f;
  const float* cb = dir ? cb_r : cb_f;
  const float* xi = xz + (long)d * NBL + b * SEQ;
  float sum = cb[d];
  #pragma unroll
  for (int k = 0; k < 4; ++k) {
    const int tt = l - 3 + k;
    if (tt >= 0) {
      const int src = dir ? (SEQ - 1 - tt) : tt;
      sum += cw[d * 4 + k] * xi[src];
    }
  }
  const float v = sum * sigmoidf_(sum);
  (dir ? xconv_r : xconv_f)[idx] = v;
}

// ---------------- xconv (d,n) fp32 -> xcT (dir, n, d) bf16 ----------------
__global__ __launch_bounds__(256) void xct_kernel(
    const float* __restrict__ xconv_f, const float* __restrict__ xconv_r,
    unsigned short* __restrict__ xcT) {
  __shared__ unsigned short tile[32][33];
  const int dir = blockIdx.z;
  const float* src = dir ? xconv_r : xconv_f;
  unsigned short* dst = xcT + (long)dir * DINNER * NBL;
  const int e0 = blockIdx.y * 32, n0 = blockIdx.x * 32;
  const int t = threadIdx.x;
  const int c = t & 31, r8 = t >> 5;
  #pragma unroll
  for (int p = 0; p < 4; ++p) {
    const int e = e0 + p * 8 + r8;
    tile[p * 8 + r8][c] = f2bf(src[(long)e * NBL + n0 + c]);
  }
  __syncthreads();
  #pragma unroll
  for (int p = 0; p < 4; ++p) {
    const int n = n0 + p * 8 + r8;
    dst[(long)n * DINNER + e0 + c] = tile[c][p * 8 + r8];
  }
}

// ---------------- x_dbl via MFMA: (64 x 1024) @ (1024n x 1024K)^T ----------
// A = xpw bf16 (64, K=1024); B = xcT (n, K). Tile 64M x 128N, 4 waves each
// owning a 32-wide n-slice. Epilogue: rows<32 -> dtT bf16 (n,32);
// rows>=32 -> xbc fp32 [n*32 + row-32].
__global__ __launch_bounds__(256) void xdbl_mfma_kernel(
    const unsigned short* __restrict__ xpwb_f, const unsigned short* __restrict__ xpwb_r,
    const unsigned short* __restrict__ xcT,
    unsigned short* __restrict__ dtT,
    float* __restrict__ xbc_f, float* __restrict__ xbc_r) {
  __shared__ unsigned short As[64 * LDK];
  __shared__ unsigned short Bs[128 * LDK];
  const int t = threadIdx.x;
  const int dir = blockIdx.y;
  const int n0 = blockIdx.x * 128;
  const unsigned short* A = dir ? xpwb_r : xpwb_f;
  const unsigned short* B = xcT + (long)dir * DINNER * NBL;
  float* xbc = dir ? xbc_r : xbc_f;
  unsigned short* dtt = dtT + (long)dir * NBL * DTRANK;

  const int lane = t & 63;
  const int w = t >> 6;
  const int fr = lane & 15;
  const int fq = lane >> 4;

  f32x4 acc[4][2];
  #pragma unroll
  for (int i = 0; i < 4; ++i)
    #pragma unroll
    for (int j = 0; j < 2; ++j) {
      f32x4 z = {0.f, 0.f, 0.f, 0.f};
      acc[i][j] = z;
    }

  const int arow = t >> 2, ako = (t & 3) * 8;   // 64 rows x 32 k
  const int brow = t >> 1, bko = (t & 1) * 16;  // 128 rows x 32 k

  for (int k0 = 0; k0 < DINNER; k0 += 32) {
    if (k0) __syncthreads();
    *(bf16x8*)&As[arow * LDK + ako] =
        *(const bf16x8*)&A[(long)arow * DINNER + k0 + ako];
    *(bf16x8*)&Bs[brow * LDK + bko] =
        *(const bf16x8*)&B[(long)(n0 + brow) * DINNER + k0 + bko];
    *(bf16x8*)&Bs[brow * LDK + bko + 8] =
        *(const bf16x8*)&B[(long)(n0 + brow) * DINNER + k0 + bko + 8];
    __syncthreads();
    bf16x8 af[4], bg[2];
    #pragma unroll
    for (int i = 0; i < 4; ++i)
      af[i] = *(const bf16x8*)&As[(i * 16 + fr) * LDK + fq * 8];
    #pragma unroll
    for (int j = 0; j < 2; ++j)
      bg[j] = *(const bf16x8*)&Bs[(w * 32 + j * 16 + fr) * LDK + fq * 8];
    #pragma unroll
    for (int i = 0; i < 4; ++i)
      #pragma unroll
      for (int j = 0; j < 2; ++j)
        acc[i][j] = __builtin_amdgcn_mfma_f32_16x16x32_bf16(
            af[i], bg[j], acc[i][j], 0, 0, 0);
  }

  #pragma unroll
  for (int i = 0; i < 4; ++i)
    #pragma unroll
    for (int j = 0; j < 2; ++j)
      #pragma unroll
      for (int r2 = 0; r2 < 4; ++r2) {
        const int m = i * 16 + fq * 4 + r2;
        const int n = n0 + w * 32 + j * 16 + fr;
        const float v = acc[i][j][r2];
        if (m < DTRANK) dtt[(long)n * DTRANK + m] = f2bf(v);
        else xbc[(long)n * 32 + (m - 32)] = v;
      }
}

// ---------------- delta via MFMA: softplus(dtw @ dt + dtb) ----------------
// A = dtwb (1024 d, K=32); B = dtT (1024 n, K=32). Single K-step.
__global__ __launch_bounds__(256) void deltam_kernel(
    const unsigned short* __restrict__ dtwb_f, const unsigned short* __restrict__ dtwb_r,
    const unsigned short* __restrict__ dtT,
    const float* __restrict__ dtb_f, const float* __restrict__ dtb_r,
    float* __restrict__ delta_f, float* __restrict__ delta_r) {
  __shared__ unsigned short As[128 * LDK];
  __shared__ unsigned short Bs[128 * LDK];
  const int t = threadIdx.x;
  const int dir = blockIdx.z;
  const unsigned short* A = dir ? dtwb_r : dtwb_f;
  const unsigned short* B = dtT + (long)dir * NBL * DTRANK;
  const float* dtb = dir ? dtb_r : dtb_f;
  float* dl = dir ? delta_r : delta_f;
  const int m0 = blockIdx.y * 128, n0 = blockIdx.x * 128;
  const int lane = t & 63;
  const int w = t >> 6;
  const int wr = (w >> 1) * 64, wc = (w & 1) * 64;
  const int fr = lane & 15;
  const int fq = lane >> 4;

  const int srow = t >> 1;
  const int sko = (t & 1) * 16;
  *(bf16x8*)&As[srow * LDK + sko] =
      *(const bf16x8*)&A[(long)(m0 + srow) * DTRANK + sko];
  *(bf16x8*)&As[srow * LDK + sko + 8] =
      *(const bf16x8*)&A[(long)(m0 + srow) * DTRANK + sko + 8];
  *(bf16x8*)&Bs[srow * LDK + sko] =
      *(const bf16x8*)&B[(long)(n0 + srow) * DTRANK + sko];
  *(bf16x8*)&Bs[srow * LDK + sko + 8] =
      *(const bf16x8*)&B[(long)(n0 + srow) * DTRANK + sko + 8];
  __syncthreads();

  bf16x8 af[4], bg[4];
  #pragma unroll
  for (int i = 0; i < 4; ++i) {
    af[i] = *(const bf16x8*)&As[(wr + i * 16 + fr) * LDK + fq * 8];
    bg[i] = *(const bf16x8*)&Bs[(wc + i * 16 + fr) * LDK + fq * 8];
  }
  f32x4 acc[4][4];
  #pragma unroll
  for (int i = 0; i < 4; ++i)
    #pragma unroll
    for (int j = 0; j < 4; ++j) {
      f32x4 z = {0.f, 0.f, 0.f, 0.f};
      acc[i][j] = __builtin_amdgcn_mfma_f32_16x16x32_bf16(af[i], bg[j], z, 0, 0, 0);
    }

  #pragma unroll
  for (int i = 0; i < 4; ++i) {
    const int m = m0 + wr + i * 16 + fq * 4;
    #pragma unroll
    for (int r2 = 0; r2 < 4; ++r2) {
      const float bias = dtb[m + r2];
      #pragma unroll
      for (int j = 0; j < 4; ++j) {
        const int n = n0 + wc + j * 16 + fr;
        dl[(long)(m + r2) * NBL + n] = softplusf_(acc[i][j][r2] + bias);
      }
    }
  }
}

// ---------------- chunked selective scan ----------------
#define NCHK 8
#define CLEN 64
__global__ __launch_bounds__(256) void scan_partA(
    const float* __restrict__ delta_f, const float* __restrict__ delta_r,
    const float* __restrict__ xconv_f, const float* __restrict__ xconv_r,
    const float* __restrict__ xbc_f, const float* __restrict__ xbc_r,
    const float* __restrict__ Alog_f, const float* __restrict__ Alog_r,
    float* __restrict__ hloc, float* __restrict__ aprd) {
  const int t = threadIdx.x;
  const int gid = blockIdx.x * 16 + (t >> 4);
  const int lane = t & 15;
  const int c = gid & (NCHK - 1);
  const int row = gid >> 3;
  const int dir = row >> 11, b = (row >> 10) & 1, d = row & 1023;
  const float* dp = (dir ? delta_r : delta_f) + (long)d * NBL + b * SEQ + c * CLEN;
  const float* up = (dir ? xconv_r : xconv_f) + (long)d * NBL + b * SEQ + c * CLEN;
  const float* bc = (dir ? xbc_r : xbc_f) + ((long)b * SEQ + c * CLEN) * 32;
  const float An = -__expf((dir ? Alog_r : Alog_f)[d * DSTATE + lane]);
  float h = 0.f, P = 1.f;
  #pragma unroll 8
  for (int l = 0; l < CLEN; ++l) {
    const float dt = dp[l], u = up[l];
    const float Bn = bc[l * 32 + lane];
    const float dA = __expf(dt * An);
    h = fmaf(h, dA, dt * u * Bn);
    P *= dA;
  }
  hloc[(long)gid * 16 + lane] = h;
  aprd[(long)gid * 16 + lane] = P;
}

__global__ __launch_bounds__(256) void scan_partB(
    const float* __restrict__ delta_f, const float* __restrict__ delta_r,
    const float* __restrict__ xconv_f, const float* __restrict__ xconv_r,
    const float* __restrict__ xbc_f, const float* __restrict__ xbc_r,
    const float* __restrict__ Alog_f, const float* __restrict__ Alog_r,
    const float* __restrict__ Dsk_f, const float* __restrict__ Dsk_r,
    const float* __restrict__ hloc, const float* __restrict__ aprd,
    const float* __restrict__ xz,
    float* __restrict__ y_f, float* __restrict__ y_r) {
  __shared__ float s_y[16][CLEN + 4];
  const int t = threadIdx.x;
  const int g = t >> 4;
  const int gid = blockIdx.x * 16 + g;
  const int lane = t & 15;
  const int c = gid & (NCHK - 1);
  const int row = gid >> 3;
  const int dir = row >> 11, b = (row >> 10) & 1, d = row & 1023;
  const float* dp = (dir ? delta_r : delta_f) + (long)d * NBL + b * SEQ + c * CLEN;
  const float* up = (dir ? xconv_r : xconv_f) + (long)d * NBL + b * SEQ + c * CLEN;
  const float* bc = (dir ? xbc_r : xbc_f) + ((long)b * SEQ + c * CLEN) * 32;
  const float An = -__expf((dir ? Alog_r : Alog_f)[d * DSTATE + lane]);
  const float Dv = (dir ? Dsk_r : Dsk_f)[d];

  float h = 0.f;
  const long base = (long)(gid & ~(NCHK - 1)) * 16 + lane;
  for (int j = 0; j < c; ++j)
    h = fmaf(h, aprd[base + j * 16], hloc[base + j * 16]);

  #pragma unroll 4
  for (int l = 0; l < CLEN; ++l) {
    const float dt = dp[l], u = up[l];
    const float Bn = bc[l * 32 + lane];
    const float Cn = bc[l * 32 + 16 + lane];
    const float dA = __expf(dt * An);
    h = fmaf(h, dA, dt * u * Bn);
    float pr = h * Cn;
    DPPADD(pr, 0x111);
    DPPADD(pr, 0x112);
    DPPADD(pr, 0x114);
    DPPADD(pr, 0x118);
    if (lane == 0) s_y[g][l] = fmaf(Dv, u, pr);
  }

  const float* zp = xz + (long)(DINNER + d) * NBL + b * SEQ;
  float* yp = (dir ? y_r : y_f) + (long)d * NBL + b * SEQ;
  #pragma unroll
  for (int k = 0; k < 4; ++k) {
    const int l = (lane << 2) + k;
    const int lg = c * CLEN + l;
    const int lo = dir ? (SEQ - 1 - lg) : lg;
    const float z = zp[lo];
    yp[lo] = s_y[g][l] * (z * sigmoidf_(z));
  }
}

// ---------------- y transpose + add + bf16 ----------------
__global__ __launch_bounds__(256) void ytrans_kernel(
    const float* __restrict__ yf, const float* __restrict__ yr,
    unsigned short* __restrict__ yt) {
  __shared__ unsigned short tile[32][33];
  const int e0 = blockIdx.y * 32, n0 = blockIdx.x * 32;
  const int t = threadIdx.x;
  const int c = t & 31, r8 = t >> 5;
  #pragma unroll
  for (int p = 0; p < 4; ++p) {
    const int e = e0 + p * 8 + r8;
    const float v = yf[(long)e * NBL + n0 + c] + yr[(long)e * NBL + n0 + c];
    tile[p * 8 + r8][c] = f2bf(v);
  }
  __syncthreads();
  #pragma unroll
  for (int p = 0; p < 4; ++p) {
    const int n = n0 + p * 8 + r8;
    yt[(long)n * DINNER + e0 + c] = tile[c][p * 8 + r8];
  }
}

extern "C" void kernel_launch(void* const* d_in, const int* in_sizes, int n_in,
                              void* d_out, int out_size, void* d_ws, size_t ws_size,
                              hipStream_t stream) {
  (void)in_sizes; (void)n_in; (void)out_size; (void)ws_size;
  const float* x       = (const float*)d_in[0];
  const float* norm_w  = (const float*)d_in[1];
  const float* in_proj = (const float*)d_in[2];
  const float* convw_f = (const float*)d_in[3];
  const float* convb_f = (const float*)d_in[4];
  const float* xpw_f   = (const float*)d_in[5];
  const float* dtw_f   = (const float*)d_in[6];
  const float* dtb_f   = (const float*)d_in[7];
  const float* Alog_f  = (const float*)d_in[8];
  const float* Dsk_f   = (const float*)d_in[9];
  const float* convw_r = (const float*)d_in[10];
  const float* convb_r = (const float*)d_in[11];
  const float* xpw_r   = (const float*)d_in[12];
  const float* dtw_r   = (const float*)d_in[13];
  const float* dtb_r   = (const float*)d_in[14];
  const float* Alog_r  = (const float*)d_in[15];
  const float* Dsk_r   = (const float*)d_in[16];
  const float* out_w   = (const float*)d_in[17];
  const float* normf_w = (const float*)d_in[18];

  float* ws = (float*)d_ws;
  float* residual = ws;  ws += 524288;
  float* ybt_f    = ws;  ws += 524288;   // 1024x1024 bf16
  float* xzbuf    = ws;  ws += 2097152;
  float* xconv_f  = ws;  ws += 1048576;
  float* xconv_r  = ws;  ws += 1048576;
  float* xbc_f    = ws;  ws += 32768;
  float* xbc_r    = ws;  ws += 32768;
  float* delta_f  = ws;  ws += 1048576;
  float* delta_r  = ws;  ws += 1048576;
  float* y_f      = ws;  ws += 1048576;
  float* y_r      = ws;  ws += 1048576;
  float* hs       = ws;  ws += 524288;
  float* hnb_f    = ws;  ws += 262144;   // 1024x512 bf16
  float* wbfin_f  = ws;  ws += 2097152;  // 4x2048x512 bf16
  float* wbfout_f = ws;  ws += 1048576;  // 4x512x1024 bf16
  float* hloc     = ws;  ws += 524288;
  float* aprd     = ws;  ws += 524288;
  float* xcT_f    = ws;  ws += 1048576;  // 2 x 1024 x 1024 bf16
  float* dtT_f    = ws;  ws += 32768;    // 2 x 1024 x 32 bf16
  float* xpwb_f_  = ws;  ws += 131072;   // 4 x 64 x 1024 bf16
  float* xpwb_r_  = ws;  ws += 131072;
  float* dtwb_f_  = ws;  ws += 65536;    // 4 x 1024 x 32 bf16
  float* dtwb_r_  = ws;  ws += 65536;

  unsigned short* ybt = (unsigned short*)ybt_f;
  unsigned short* hnb = (unsigned short*)hnb_f;
  unsigned short* wbfin = (unsigned short*)wbfin_f;
  unsigned short* wbfout = (unsigned short*)wbfout_f;
  unsigned short* xcT = (unsigned short*)xcT_f;
  unsigned short* dtT = (unsigned short*)dtT_f;
  unsigned short* xpwb_f = (unsigned short*)xpwb_f_;
  unsigned short* xpwb_r = (unsigned short*)xpwb_r_;
  unsigned short* dtwb_f = (unsigned short*)dtwb_f_;
  unsigned short* dtwb_r = (unsigned short*)dtwb_r_;

  float* outp = (float*)d_out;

  // all-layer weight conversion up front
  tobf16_kernel<<<2048, 256, 0, stream>>>(in_proj, wbfin, 4 * 2048 * 512);
  tobf16_kernel<<<1024, 256, 0, stream>>>(out_w, wbfout, 4 * 512 * 1024);
  tobf16_kernel<<<128, 256, 0, stream>>>(xpw_f, xpwb_f, 4 * 64 * DINNER);
  tobf16_kernel<<<128, 256, 0, stream>>>(xpw_r, xpwb_r, 4 * 64 * DINNER);
  tobf16_kernel<<<64, 256, 0, stream>>>(dtw_f, dtwb_f, 4 * DINNER * DTRANK);
  tobf16_kernel<<<64, 256, 0, stream>>>(dtw_r, dtwb_r, 4 * DINNER * DTRANK);

  for (int layer = 0; layer < 4; ++layer) {
    addnorm_kernel<<<1024, 256, 0, stream>>>(
        layer == 0 ? x : hs, residual, norm_w + layer * DMODEL,
        nullptr, hnb, layer == 0 ? 1 : 0);
    gemm_mfma_kernel<<<dim3(8, 16), 256, 0, stream>>>(
        wbfin + (long)layer * 2048 * 512, hnb, xzbuf, nullptr, 512, 1024, 1);
    conv_silu_kernel<<<dim3(4096, 2), 256, 0, stream>>>(
        xzbuf, convw_f + layer * DINNER * 4, convb_f + layer * DINNER,
        convw_r + layer * DINNER * 4, convb_r + layer * DINNER, xconv_f, xconv_r);
    xct_kernel<<<dim3(32, 32, 2), 256, 0, stream>>>(xconv_f, xconv_r, xcT);
    xdbl_mfma_kernel<<<dim3(8, 2), 256, 0, stream>>>(
        xpwb_f + (long)layer * 64 * DINNER, xpwb_r + (long)layer * 64 * DINNER,
        xcT, dtT, xbc_f, xbc_r);
    deltam_kernel<<<dim3(8, 8, 2), 256, 0, stream>>>(
        dtwb_f + (long)layer * DINNER * DTRANK, dtwb_r + (long)layer * DINNER * DTRANK,
        dtT, dtb_f + layer * DINNER, dtb_r + layer * DINNER, delta_f, delta_r);
    scan_partA<<<2048, 256, 0, stream>>>(
        delta_f, delta_r, xconv_f, xconv_r, xbc_f, xbc_r,
        Alog_f + layer * DINNER * DSTATE, Alog_r + layer * DINNER * DSTATE,
        hloc, aprd);
    scan_partB<<<2048, 256, 0, stream>>>(
        delta_f, delta_r, xconv_f, xconv_r, xbc_f, xbc_r,
        Alog_f + layer * DINNER * DSTATE, Alog_r + layer * DINNER * DSTATE,
        Dsk_f + layer * DINNER, Dsk_r + layer * DINNER,
        hloc, aprd, xzbuf, y_f, y_r);
    ytrans_kernel<<<dim3(32, 32), 256, 0, stream>>>(y_f, y_r, ybt);
    gemm_mfma_kernel<<<dim3(8, 4), 256, 0, stream>>>(
        wbfout + (long)layer * 512 * 1024, ybt, hs,
        outp + (long)(1 + layer) * 524288, 1024, 1, 512);
  }
  addnorm_kernel<<<1024, 256, 0, stream>>>(hs, residual, normf_w, outp, nullptr, 0);
}